// Round 19
// baseline (134.972 us; speedup 1.0000x reference)
//
#include <hip/hip_runtime.h>
#include <cstdint>

#define B_SZ   16384
#define H_SZ   512
#define DIN    256
#define TEMB   16
#define KP     1344            // packed K: x[0,256) h[256,768) c[768,1280) delt[1280,1296) pad
#define KPB    1344            // bytes per row (i8)
#define BH     8388608L        // B_SZ*H_SZ
#define SLOT   16384           // main slot: A only, 256 rows x 64 B
#define TSLOT  20480           // tgate slot: A 16 KB + 2 W regions x 2 KB
#define GSTR   688128          // 512*KPB: gate stride in Wp8 bytes

typedef __attribute__((ext_vector_type(4))) float f32x4;
typedef __attribute__((ext_vector_type(4))) int   i32x4;

typedef const __attribute__((address_space(1))) unsigned int gu32_t;
typedef __attribute__((address_space(3)))       unsigned int lu32_t;

__device__ __forceinline__ void gld16(const void* g, void* l) {
  __builtin_amdgcn_global_load_lds((gu32_t*)(uintptr_t)g,
                                   (lu32_t*)(unsigned int)(uintptr_t)l, 16, 0, 0);
}

__device__ __forceinline__ float sigm(float v)  { return 1.0f / (1.0f + __expf(-v)); }
__device__ __forceinline__ float tanhx(float v) { return 2.0f / (1.0f + __expf(-2.0f * v)) - 1.0f; }

__device__ __forceinline__ signed char q8(float v, float inv) {
  int q = __float2int_rn(v * inv);
  q = (q > 127) ? 127 : (q < -127 ? -127 : q);
  return (signed char)q;
}

// ---------------- fused prep: blocks [0,4096) quantize A rows; [4096,7168) quantize W rows ----
__global__ void prep_kernel(const float* __restrict__ x, const float* __restrict__ h,
                            const float* __restrict__ c, const float* __restrict__ dl,
                            const float* __restrict__ Wix, const float* __restrict__ Wih, const float* __restrict__ Wic,
                            const float* __restrict__ Wfx, const float* __restrict__ Wfh, const float* __restrict__ Wfc,
                            const float* __restrict__ Wtx, const float* __restrict__ Wtt,
                            const float* __restrict__ Wcx, const float* __restrict__ Wch,
                            const float* __restrict__ Wox, const float* __restrict__ Woh,
                            const float* __restrict__ Woc, const float* __restrict__ Wot,
                            signed char* __restrict__ Ap, float* __restrict__ sa,
                            signed char* __restrict__ Wp, float* __restrict__ sw) {
  __shared__ float row[KP];
  __shared__ float red[256];
  const int tid = threadIdx.x;
  if (blockIdx.x < 4096) {
    // ---- A rows: wave-per-row, no LDS/barriers ----
    const int lane = tid & 63;
    const int m    = blockIdx.x * 4 + (tid >> 6);
    float4 v[6];
    float lmax = 0.f;
#pragma unroll
    for (int i = 0; i < 6; ++i) {
      const int k4 = (i * 64 + lane) * 4;
      float4 t = make_float4(0.f, 0.f, 0.f, 0.f);
      if (k4 < 256)       t = *(const float4*)(x  + (size_t)m * DIN  + k4);
      else if (k4 < 768)  t = *(const float4*)(h  + (size_t)m * H_SZ + (k4 - 256));
      else if (k4 < 1280) t = *(const float4*)(c  + (size_t)m * H_SZ + (k4 - 768));
      else if (k4 < 1296) t = *(const float4*)(dl + (size_t)m * TEMB + (k4 - 1280));
      v[i] = t;
      lmax = fmaxf(lmax, fmaxf(fmaxf(fabsf(t.x), fabsf(t.y)), fmaxf(fabsf(t.z), fabsf(t.w))));
    }
#pragma unroll
    for (int s = 1; s < 64; s <<= 1)
      lmax = fmaxf(lmax, __shfl_xor(lmax, s));
    const float smax = fmaxf(lmax, 1e-20f);
    const float inv  = 127.0f / smax;
    if (lane == 0) sa[m] = smax * (1.0f / 127.0f);
#pragma unroll
    for (int i = 0; i < 6; ++i) {
      const int k4 = (i * 64 + lane) * 4;
      if (k4 < KP) {
        char4 o;
        o.x = q8(v[i].x, inv); o.y = q8(v[i].y, inv);
        o.z = q8(v[i].z, inv); o.w = q8(v[i].w, inv);
        *(char4*)(Ap + (size_t)m * KPB + k4) = o;
      }
    }
    return;
  }
  // ---- W rows ----
  const int R = blockIdx.x - 4096;   // 0..3071
  const int g = R >> 9;
  const int n = R & 511;
  float lmax = 0.f;
  for (int i = tid; i < KP / 4; i += 256) {
    const int k4 = i * 4;
    const float* src = nullptr; long o = 0;
    if (g == 0) {
      if (k4 < 256)       { src = Wix; o = (long)n * 256 + k4; }
      else if (k4 < 768)  { src = Wih; o = (long)n * 512 + (k4 - 256); }
      else if (k4 < 1280) { src = Wic; o = (long)n * 512 + (k4 - 768); }
    } else if (g == 1) {
      if (k4 < 256)       { src = Wfx; o = (long)n * 256 + k4; }
      else if (k4 < 768)  { src = Wfh; o = (long)n * 512 + (k4 - 256); }
      else if (k4 < 1280) { src = Wfc; o = (long)n * 512 + (k4 - 768); }
    } else if (g == 2) {
      if (k4 < 256)       { src = Wtx; o = (long)n * 256 + k4; }
    } else if (g == 3) {
      if (k4 < 256)       { src = Wcx; o = (long)n * 256 + k4; }
      else if (k4 < 768)  { src = Wch; o = (long)n * 512 + (k4 - 256); }
    } else if (g == 4) {
      if (k4 < 256)       { src = Wox; o = (long)n * 256 + k4; }
      else if (k4 < 768)  { src = Woh; o = (long)n * 512 + (k4 - 256); }
      else if (k4 < 1280) { src = Woc; o = (long)n * 512 + (k4 - 768); }
      else if (k4 < 1296) { src = Wot; o = (long)n * 16 + (k4 - 1280); }
    } else {
      if (k4 >= 1280 && k4 < 1296) { src = Wtt; o = (long)n * 16 + (k4 - 1280); }
    }
    float4 v = make_float4(0.f, 0.f, 0.f, 0.f);
    if (src) v = *(const float4*)(src + o);
    *(float4*)(row + k4) = v;
    lmax = fmaxf(lmax, fmaxf(fmaxf(fabsf(v.x), fabsf(v.y)), fmaxf(fabsf(v.z), fabsf(v.w))));
  }
  red[tid] = lmax;
  __syncthreads();
  for (int s = 128; s > 0; s >>= 1) {
    if (tid < s) red[tid] = fmaxf(red[tid], red[tid + s]);
    __syncthreads();
  }
  const float smax = fmaxf(red[0], 1e-20f);
  const float inv  = 127.0f / smax;
  if (tid == 0) sw[R] = smax * (1.0f / 127.0f);
  for (int i = tid; i < KP / 4; i += 256) {
    const int k4 = i * 4;
    char4 o;
    o.x = q8(row[k4],     inv); o.y = q8(row[k4 + 1], inv);
    o.z = q8(row[k4 + 2], inv); o.w = q8(row[k4 + 3], inv);
    *(char4*)(Wp + (size_t)R * KPB + k4) = o;
  }
}

// ---------------- main kernel: A via LDS ring-3; W (B-operand) DIRECT from L2 ----------------
// LDS slot = A only: byte = row*64 + ((kgrp+(lrow>>1))&3)*16, row in [0,256).
// B-frag is linear in Wp8: lane reads row (bcol+wcg+lrow), bytes h*64 + kgrp*16.
// A stage: wave w -> chunks {2w,2w+1} = rows [32w,32w+32); 2 gld16/wave/phase.

__device__ __forceinline__ void stageA(char* lds, int sb, int ht,
                                       const char* sAb, int wid) {
  const unsigned kb = (unsigned)ht * 64u;
  gld16(sAb + kb,             lds + sb + wid * 2048);
  gld16(sAb + kb + 16u * KPB, lds + sb + wid * 2048 + 1024);
}

// phase: entry vmcnt(NWE) ensures stage(h) landed (stage(h+1) may stay in flight);
// barrier publishes CU-wide; then plain-C LDS a-reads, L2 b-loads, stage(h+2).
// Compiler inserts minimal lgkm/vm waits before the MFMA cluster (b-wait leaves
// stage(h+2) outstanding). Ring-3 WAR safety: slot (h+2)%3's readers completed
// their (compiler-waited) ds_reads before passing barrier(h).
template<unsigned CM, int NWE, bool ST>
__device__ __forceinline__ void phase(char* lds, int rs, int ws, int ht,
    const char* sAb, const char* wbase, int h, int wid, int aro, i32x4 acc[4][4]) {
  asm volatile("s_waitcnt vmcnt(%0)" :: "i"(NWE) : "memory");
  __builtin_amdgcn_s_barrier();
  __builtin_amdgcn_sched_barrier(0);
  const char* base = lds + rs;
  i32x4 a[4];
#pragma unroll
  for (int i = 0; i < 4; ++i)
    a[i] = *(const i32x4*)(base + aro + i * 1024);
  const size_t kb = (size_t)h * 64;
  i32x4 b[4];
  if (CM & 1u) b[0] = *(const i32x4*)(wbase + 0 * (size_t)GSTR + kb);
  if (CM & 2u) b[1] = *(const i32x4*)(wbase + 1 * (size_t)GSTR + kb);
  if (CM & 4u) b[2] = *(const i32x4*)(wbase + 3 * (size_t)GSTR + kb);
  if (CM & 8u) b[3] = *(const i32x4*)(wbase + 4 * (size_t)GSTR + kb);
  if (ST) stageA(lds, ws, ht, sAb, wid);
  __builtin_amdgcn_sched_barrier(0);
  __builtin_amdgcn_s_setprio(1);
#pragma unroll
  for (int r = 0; r < 4; ++r) {
    if (CM & (1u << r)) {
#pragma unroll
      for (int i = 0; i < 4; ++i)
        acc[r][i] = __builtin_amdgcn_mfma_i32_16x16x64_i8(a[i], b[r], acc[r][i], 0, 0, 0);
    }
  }
  __builtin_amdgcn_s_setprio(0);
}

// acc[4][4]=64 + arch ~60 <= 128/wave -> 4 waves/SIMD; LDS 3*16384*2 wgs = 96 KB.
__global__ __launch_bounds__(512, 4) void lstm_main(
    const signed char* __restrict__ Ap, const signed char* __restrict__ Wp,
    const float* __restrict__ sa, const float* __restrict__ sw,
    const float* __restrict__ c_prev,
    const float* __restrict__ b_ix, const float* __restrict__ b_fx,
    const float* __restrict__ b_cx, const float* __restrict__ b_ox,
    float* __restrict__ out)
{
  __shared__ __align__(16) char lds[3 * SLOT];   // 49152 B -> 2 wgs/CU

  const int tid  = threadIdx.x;
  const int lane = tid & 63;
  const int wid  = tid >> 6;

  const int bid = blockIdx.x;
  const int xcd = bid & 7;
  const int idx = bid >> 3;                  // 0..127
  const int cb  = (xcd << 1) | (idx & 1);    // 0..15
  const int rb  = idx >> 1;                  // 0..63
  const unsigned brow = (unsigned)rb * 256u;
  const int bcol = cb * 32;

  const int wr  = (wid >> 1) * 64;           // wave rows [wr, wr+64)
  const int wcg = (wid & 1) * 16;            // wave cols [wcg, wcg+16)
  const int lrow = lane & 15;
  const int kgrp = lane >> 4;

  i32x4 acc[4][4];
  {
    i32x4 z = {0, 0, 0, 0};
#pragma unroll
    for (int g = 0; g < 4; ++g)
#pragma unroll
      for (int i = 0; i < 4; ++i) acc[g][i] = z;
  }

  const int sread = ((kgrp + (lrow >> 1)) & 3) << 4;
  const int aro = (wr + lrow) * 64 + sread;

  const int l4 = lane >> 2;
  const int kslot = (((lane & 3) - ((lane >> 3) & 3)) & 3) << 4;
  const char* sAb   = (const char*)Ap + (size_t)(brow + wid * 32 + l4) * KPB + kslot;
  const char* wbase = (const char*)Wp + (size_t)(bcol + wcg + lrow) * KPB + kgrp * 16;

  // prologue: A half-tiles 0,1 in flight
  stageA(lds, 0,    0, sAb, wid);
  stageA(lds, SLOT, 1, sAb, wid);

  int rs = 0;
#define PH(CMv, NWEv, STv, HT, H) do {                                         \
    int ws = (rs >= SLOT) ? rs - SLOT : rs + 2 * SLOT;                         \
    phase<CMv, NWEv, STv>(lds, rs, ws, HT, sAb, wbase, H, wid, aro, acc);      \
    rs = (rs == 2 * SLOT) ? 0 : rs + SLOT;                                     \
  } while (0)

  // comp masks: h0-11 x+h (0xF) | h12-19 c (0xB) | h20 delt (0x8)
#pragma unroll 1
  for (int h = 0; h < 12; ++h) PH(0xF, 2, true, h + 2, h);
#pragma unroll 1
  for (int h = 12; h < 19; ++h) PH(0xB, 2, true, h + 2, h);
  PH(0xB, 2, false, 0, 19);    // stage(20) still in flight
  PH(0x8, 0, false, 0, 20);    // drain
#undef PH

  // ---------------- fused epilogue (dequant + activations; Tv precomputed) ----------------
  const float* Tvp = out + 2 * BH;
  const int n = bcol + wcg + lrow;
  const float bi = b_ix[n], bff = b_fx[n], bc = b_cx[n], bo = b_ox[n];
  const float s0 = sw[0 * 512 + n], s1 = sw[1 * 512 + n];
  const float s3 = sw[3 * 512 + n], s4 = sw[4 * 512 + n];
  const int rbase = kgrp * 4;
#pragma unroll
  for (int i = 0; i < 4; ++i) {
    const int m0 = (int)brow + wr + 16 * i + rbase;
    const float4 sa4 = *(const float4*)(sa + m0);
#pragma unroll
    for (int r = 0; r < 4; ++r) {
      const long m   = m0 + r;
      const long off = m * H_SZ + n;
      const float sr = (r == 0) ? sa4.x : (r == 1) ? sa4.y : (r == 2) ? sa4.z : sa4.w;
      const float iv = sigm((float)acc[0][i][r] * sr * s0 + bi);
      const float fv = sigm((float)acc[1][i][r] * sr * s1 + bff);
      const float kv = tanhx((float)acc[2][i][r] * sr * s3 + bc);
      const float ov = sigm((float)acc[3][i][r] * sr * s4 + bo);
      const float Tv = Tvp[off];
      const float cp = c_prev[off];
      const float cn = iv * Tv * kv + fv * cp;
      out[off]      = ov * tanhx(cn);
      out[BH + off] = cn;
    }
  }
}

// ---------------- tgate: Tv = sigm(x@Wtx^T + b_tx + sigm(delt@Wtt^T)) -> out[2BH..] ----------
template<unsigned SMASK>
__device__ __forceinline__ void stage_t(char* lds, int sb, int ht,
                                        const char* sAb, const char* sWb, int wid) {
  const unsigned kb = (unsigned)ht * 64u;
  gld16(sAb + kb,              lds + sb + wid * 2048);
  gld16(sAb + kb + 16u * KPB,  lds + sb + wid * 2048 + 1024);
  if (wid < 4) {
    const int r = wid >> 1, c = wid & 1;
    if (SMASK & (1u << r)) {
      const int g = (r == 0) ? 2 : 5;
      gld16(sWb + (unsigned)g * GSTR + (unsigned)c * (16u * KPB) + kb,
            lds + sb + 16384 + r * 2048 + c * 1024);
    }
  }
}

template<unsigned CM>
__device__ __forceinline__ void comp_t(const char* lds, int sb, int aro, int wro,
                                       i32x4 acc[2][4]) {
  const char* base = lds + sb;
  i32x4 a[4];
#pragma unroll
  for (int i = 0; i < 4; ++i)
    a[i] = *(const i32x4*)(base + aro + i * 1024);
#pragma unroll
  for (int r = 0; r < 2; ++r) {
    if (CM & (1u << r)) {
      i32x4 b = *(const i32x4*)(base + 16384 + r * 2048 + wro);
#pragma unroll
      for (int i = 0; i < 4; ++i)
        acc[r][i] = __builtin_amdgcn_mfma_i32_16x16x64_i8(a[i], b, acc[r][i], 0, 0, 0);
    }
  }
}

__global__ __launch_bounds__(512, 4) void tgate_kernel(
    const signed char* __restrict__ Ap, const signed char* __restrict__ Wp,
    const float* __restrict__ sa, const float* __restrict__ sw,
    const float* __restrict__ b_tx, float* __restrict__ out)
{
  __shared__ __align__(16) char lds[2 * TSLOT];   // 40960 B

  const int tid  = threadIdx.x;
  const int lane = tid & 63;
  const int wid  = tid >> 6;

  const int bid = blockIdx.x;
  const int xcd = bid & 7;
  const int idx = bid >> 3;
  const int cb  = (xcd << 1) | (idx & 1);
  const int rb  = idx >> 1;
  const unsigned brow = (unsigned)rb * 256u;
  const int bcol = cb * 32;

  const int wr  = (wid >> 1) * 64;
  const int wcg = (wid & 1) * 16;
  const int lrow = lane & 15;
  const int kgrp = lane >> 4;

  i32x4 acc[2][4];
  {
    i32x4 z = {0, 0, 0, 0};
#pragma unroll
    for (int g = 0; g < 2; ++g)
#pragma unroll
      for (int i = 0; i < 4; ++i) acc[g][i] = z;
  }

  const int sread = ((kgrp + (lrow >> 1)) & 3) << 4;
  const int aro = (wr + lrow) * 64 + sread;
  const int wro = (wcg + lrow) * 64 + sread;

  const int l4 = lane >> 2;
  const int kslot = (((lane & 3) - ((lane >> 3) & 3)) & 3) << 4;
  const char* sAb = (const char*)Ap + (size_t)(brow + wid * 32 + l4) * KPB + kslot;
  const char* sWb = (const char*)Wp + (size_t)(bcol + l4) * KPB + kslot;

  stage_t<0x1>(lds, 0, 0, sAb, sWb, wid);
  __syncthreads();
  stage_t<0x1>(lds, TSLOT, 1, sAb, sWb, wid);
  comp_t<0x1>(lds, 0, aro, wro, acc);
  __syncthreads();
  stage_t<0x1>(lds, 0, 2, sAb, sWb, wid);
  comp_t<0x1>(lds, TSLOT, aro, wro, acc);
  __syncthreads();
  stage_t<0x1>(lds, TSLOT, 3, sAb, sWb, wid);
  comp_t<0x1>(lds, 0, aro, wro, acc);
  __syncthreads();
  stage_t<0x2>(lds, 0, 20, sAb, sWb, wid);     // delt segment (bytes 1280-1343)
  comp_t<0x1>(lds, TSLOT, aro, wro, acc);
  __syncthreads();
  comp_t<0x2>(lds, 0, aro, wro, acc);

  const int n = bcol + wcg + lrow;
  const float bt = b_tx[n];
  const float s2 = sw[2 * 512 + n], s5 = sw[5 * 512 + n];
  const int rbase = kgrp * 4;
#pragma unroll
  for (int i = 0; i < 4; ++i) {
    const int m0 = (int)brow + wr + 16 * i + rbase;
    const float4 sa4 = *(const float4*)(sa + m0);
#pragma unroll
    for (int r = 0; r < 4; ++r) {
      const long off = (long)(m0 + r) * H_SZ + n;
      const float sr = (r == 0) ? sa4.x : (r == 1) ? sa4.y : (r == 2) ? sa4.z : sa4.w;
      const float inner = sigm((float)acc[1][i][r] * sr * s5);
      out[2 * BH + off] = sigm((float)acc[0][i][r] * sr * s2 + bt + inner);
    }
  }
}

extern "C" void kernel_launch(void* const* d_in, const int* in_sizes, int n_in,
                              void* d_out, int out_size, void* d_ws, size_t ws_size,
                              hipStream_t stream) {
  const float* x      = (const float*)d_in[0];
  const float* h      = (const float*)d_in[1];
  const float* c_prev = (const float*)d_in[2];
  const float* dl     = (const float*)d_in[3];
  const float* W_ix = (const float*)d_in[4];
  const float* b_ix = (const float*)d_in[5];
  const float* W_ih = (const float*)d_in[6];
  const float* W_ic = (const float*)d_in[7];
  const float* W_fx = (const float*)d_in[8];
  const float* b_fx = (const float*)d_in[9];
  const float* W_fh = (const float*)d_in[10];
  const float* W_fc = (const float*)d_in[11];
  const float* W_tx = (const float*)d_in[12];
  const float* b_tx = (const float*)d_in[13];
  const float* W_tt = (const float*)d_in[14];
  const float* W_cx = (const float*)d_in[15];
  const float* b_cx = (const float*)d_in[16];
  const float* W_ch = (const float*)d_in[17];
  const float* W_ox = (const float*)d_in[18];
  const float* b_ox = (const float*)d_in[19];
  const float* W_oh = (const float*)d_in[20];
  const float* W_oc = (const float*)d_in[21];
  const float* W_ot = (const float*)d_in[22];

  signed char* Ap8 = (signed char*)d_ws;                             // 22,020,096 B
  signed char* Wp8 = (signed char*)d_ws + (size_t)B_SZ * KPB;        // + 4,128,768 B
  float* sa = (float*)((char*)d_ws + (size_t)B_SZ * KPB + 6L * H_SZ * KPB);   // 64 KB
  float* sw = sa + B_SZ;                                             // 12 KB

  prep_kernel<<<4096 + 3072, 256, 0, stream>>>(
      x, h, c_prev, dl,
      W_ix, W_ih, W_ic, W_fx, W_fh, W_fc, W_tx, W_tt, W_cx, W_ch,
      W_ox, W_oh, W_oc, W_ot, Ap8, sa, Wp8, sw);

  tgate_kernel<<<1024, 512, 0, stream>>>(Ap8, Wp8, sa, sw, b_tx, (float*)d_out);

  lstm_main<<<1024, 512, 0, stream>>>(Ap8, Wp8, sa, sw, c_prev,
                                      b_ix, b_fx, b_cx, b_ox,
                                      (float*)d_out);
}

// Round 20
// 117.779 us; speedup vs baseline: 1.1460x; 1.1460x over previous
//
#include <hip/hip_runtime.h>
#include <cstdint>

#define B_SZ   16384
#define H_SZ   512
#define DIN    256
#define TEMB   16
#define KP     1344            // packed K: x[0,256) h[256,768) c[768,1280) delt[1280,1296) pad
#define KPB    1344            // bytes per row (i8)
#define BH     8388608L        // B_SZ*H_SZ
#define SLOT   24576           // main slot: A 16 KB (256 rows x 64 B) + 4 W regions x 2 KB
#define TSLOT  36864           // tgate slot: A 32 KB (512 rows) + 2 W regions x 2 KB
#define GSTR   688128          // 512*KPB: gate stride in Wp8 bytes

typedef __attribute__((ext_vector_type(4))) float f32x4;
typedef __attribute__((ext_vector_type(4))) int   i32x4;

typedef const __attribute__((address_space(1))) unsigned int gu32_t;
typedef __attribute__((address_space(3)))       unsigned int lu32_t;

__device__ __forceinline__ void gld16(const void* g, void* l) {
  __builtin_amdgcn_global_load_lds((gu32_t*)(uintptr_t)g,
                                   (lu32_t*)(unsigned int)(uintptr_t)l, 16, 0, 0);
}

__device__ __forceinline__ float sigm(float v)  { return 1.0f / (1.0f + __expf(-v)); }
__device__ __forceinline__ float tanhx(float v) { return 2.0f / (1.0f + __expf(-2.0f * v)) - 1.0f; }

__device__ __forceinline__ signed char q8(float v, float inv) {
  int q = __float2int_rn(v * inv);
  q = (q > 127) ? 127 : (q < -127 ? -127 : q);
  return (signed char)q;
}

// ---------------- fused prep: blocks [0,4096) quantize A rows; [4096,7168) quantize W rows ----
__global__ void prep_kernel(const float* __restrict__ x, const float* __restrict__ h,
                            const float* __restrict__ c, const float* __restrict__ dl,
                            const float* __restrict__ Wix, const float* __restrict__ Wih, const float* __restrict__ Wic,
                            const float* __restrict__ Wfx, const float* __restrict__ Wfh, const float* __restrict__ Wfc,
                            const float* __restrict__ Wtx, const float* __restrict__ Wtt,
                            const float* __restrict__ Wcx, const float* __restrict__ Wch,
                            const float* __restrict__ Wox, const float* __restrict__ Woh,
                            const float* __restrict__ Woc, const float* __restrict__ Wot,
                            signed char* __restrict__ Ap, float* __restrict__ sa,
                            signed char* __restrict__ Wp, float* __restrict__ sw) {
  __shared__ float row[KP];
  __shared__ float red[256];
  const int tid = threadIdx.x;
  if (blockIdx.x < 4096) {
    const int lane = tid & 63;
    const int m    = blockIdx.x * 4 + (tid >> 6);
    float4 v[6];
    float lmax = 0.f;
#pragma unroll
    for (int i = 0; i < 6; ++i) {
      const int k4 = (i * 64 + lane) * 4;
      float4 t = make_float4(0.f, 0.f, 0.f, 0.f);
      if (k4 < 256)       t = *(const float4*)(x  + (size_t)m * DIN  + k4);
      else if (k4 < 768)  t = *(const float4*)(h  + (size_t)m * H_SZ + (k4 - 256));
      else if (k4 < 1280) t = *(const float4*)(c  + (size_t)m * H_SZ + (k4 - 768));
      else if (k4 < 1296) t = *(const float4*)(dl + (size_t)m * TEMB + (k4 - 1280));
      v[i] = t;
      lmax = fmaxf(lmax, fmaxf(fmaxf(fabsf(t.x), fabsf(t.y)), fmaxf(fabsf(t.z), fabsf(t.w))));
    }
#pragma unroll
    for (int s = 1; s < 64; s <<= 1)
      lmax = fmaxf(lmax, __shfl_xor(lmax, s));
    const float smax = fmaxf(lmax, 1e-20f);
    const float inv  = 127.0f / smax;
    if (lane == 0) sa[m] = smax * (1.0f / 127.0f);
#pragma unroll
    for (int i = 0; i < 6; ++i) {
      const int k4 = (i * 64 + lane) * 4;
      if (k4 < KP) {
        char4 o;
        o.x = q8(v[i].x, inv); o.y = q8(v[i].y, inv);
        o.z = q8(v[i].z, inv); o.w = q8(v[i].w, inv);
        *(char4*)(Ap + (size_t)m * KPB + k4) = o;
      }
    }
    return;
  }
  const int R = blockIdx.x - 4096;   // 0..3071
  const int g = R >> 9;
  const int n = R & 511;
  float lmax = 0.f;
  for (int i = tid; i < KP / 4; i += 256) {
    const int k4 = i * 4;
    const float* src = nullptr; long o = 0;
    if (g == 0) {
      if (k4 < 256)       { src = Wix; o = (long)n * 256 + k4; }
      else if (k4 < 768)  { src = Wih; o = (long)n * 512 + (k4 - 256); }
      else if (k4 < 1280) { src = Wic; o = (long)n * 512 + (k4 - 768); }
    } else if (g == 1) {
      if (k4 < 256)       { src = Wfx; o = (long)n * 256 + k4; }
      else if (k4 < 768)  { src = Wfh; o = (long)n * 512 + (k4 - 256); }
      else if (k4 < 1280) { src = Wfc; o = (long)n * 512 + (k4 - 768); }
    } else if (g == 2) {
      if (k4 < 256)       { src = Wtx; o = (long)n * 256 + k4; }
    } else if (g == 3) {
      if (k4 < 256)       { src = Wcx; o = (long)n * 256 + k4; }
      else if (k4 < 768)  { src = Wch; o = (long)n * 512 + (k4 - 256); }
    } else if (g == 4) {
      if (k4 < 256)       { src = Wox; o = (long)n * 256 + k4; }
      else if (k4 < 768)  { src = Woh; o = (long)n * 512 + (k4 - 256); }
      else if (k4 < 1280) { src = Woc; o = (long)n * 512 + (k4 - 768); }
      else if (k4 < 1296) { src = Wot; o = (long)n * 16 + (k4 - 1280); }
    } else {
      if (k4 >= 1280 && k4 < 1296) { src = Wtt; o = (long)n * 16 + (k4 - 1280); }
    }
    float4 v = make_float4(0.f, 0.f, 0.f, 0.f);
    if (src) v = *(const float4*)(src + o);
    *(float4*)(row + k4) = v;
    lmax = fmaxf(lmax, fmaxf(fmaxf(fabsf(v.x), fabsf(v.y)), fmaxf(fabsf(v.z), fabsf(v.w))));
  }
  red[tid] = lmax;
  __syncthreads();
  for (int s = 128; s > 0; s >>= 1) {
    if (tid < s) red[tid] = fmaxf(red[tid], red[tid + s]);
    __syncthreads();
  }
  const float smax = fmaxf(red[0], 1e-20f);
  const float inv  = 127.0f / smax;
  if (tid == 0) sw[R] = smax * (1.0f / 127.0f);
  for (int i = tid; i < KP / 4; i += 256) {
    const int k4 = i * 4;
    char4 o;
    o.x = q8(row[k4],     inv); o.y = q8(row[k4 + 1], inv);
    o.z = q8(row[k4 + 2], inv); o.w = q8(row[k4 + 3], inv);
    *(char4*)(Wp + (size_t)R * KPB + k4) = o;
  }
}

// LDS layout per main slot (K-phase = 64 i8 = 64 B per row; r11/r16/r17/r18-verified):
//   A: byte = row*64 + ((kgrp + (lrow>>1))&3)*16,  row in [0,256)
//   W: byte = 16384 + region*2048 + col*64 + swz,  col in [0,32)
// regions {0,1,2,3} = gates {i=0,f=1,k=3,o=4}; inactive K-segments in Wp are ZERO,
// so staging is mask-free (uniform 3 loads/wave -> compile-time vmcnt immediates).

__device__ __forceinline__ void stage(char* lds, int sb, int ht,
                                      const char* sAb, const char* sWb, int wid) {
  const unsigned kb = (unsigned)ht * 64u;
  gld16(sAb + kb,              lds + sb + wid * 2048);
  gld16(sAb + kb + 16u * KPB,  lds + sb + wid * 2048 + 1024);
  const int r = wid >> 1, c = wid & 1;        // region, col-half (wave-uniform)
  const int g = r + (r >> 1);                 // region -> gate: 0,1,3,4
  gld16(sWb + (unsigned)g * GSTR + (unsigned)c * (16u * KPB) + kb,
        lds + sb + 16384 + r * 2048 + c * 1024);
}

// single-barrier counted-vmcnt phase (ring-3; r18-proven at 2 wgs/CU)
template<unsigned CM, int NW, bool ST>
__device__ __forceinline__ void phase(char* lds, int rs, int ws, int ht,
    const char* sAb, const char* sWb, int wid, int aro, int wro, i32x4 acc[4][4]) {
  asm volatile("s_waitcnt vmcnt(%0)" :: "i"(NW) : "memory");
  __builtin_amdgcn_s_barrier();
  __builtin_amdgcn_sched_barrier(0);
  const char* base = lds + rs;
  i32x4 a[4];
#pragma unroll
  for (int i = 0; i < 4; ++i)
    a[i] = *(const i32x4*)(base + aro + i * 1024);
  i32x4 b[4];
#pragma unroll
  for (int r = 0; r < 4; ++r)
    if (CM & (1u << r))
      b[r] = *(const i32x4*)(base + 16384 + r * 2048 + wro);
  if (ST) stage(lds, ws, ht, sAb, sWb, wid);   // issue-only; rides vmcnt
  asm volatile("s_waitcnt lgkmcnt(0)" ::: "memory");
  __builtin_amdgcn_sched_barrier(0);
  __builtin_amdgcn_s_setprio(1);
#pragma unroll
  for (int r = 0; r < 4; ++r) {
    if (CM & (1u << r)) {
#pragma unroll
      for (int i = 0; i < 4; ++i)
        acc[r][i] = __builtin_amdgcn_mfma_i32_16x16x64_i8(a[i], b[r], acc[r][i], 0, 0, 0);
    }
  }
  __builtin_amdgcn_s_setprio(0);
}

// ---------------- main fused kernel (4 gates i,f,k,o; 21 phases, ring-3; r18) ----------------
__global__ __launch_bounds__(512, 4) void lstm_main(
    const signed char* __restrict__ Ap, const signed char* __restrict__ Wp,
    const float* __restrict__ sa, const float* __restrict__ sw,
    const float* __restrict__ c_prev,
    const float* __restrict__ b_ix, const float* __restrict__ b_fx,
    const float* __restrict__ b_cx, const float* __restrict__ b_ox,
    float* __restrict__ out)
{
  __shared__ __align__(16) char lds[3 * SLOT];   // 73728 B -> 2 wgs/CU

  const int tid  = threadIdx.x;
  const int lane = tid & 63;
  const int wid  = tid >> 6;

  const int bid = blockIdx.x;
  const int xcd = bid & 7;
  const int idx = bid >> 3;                  // 0..127
  const int cb  = (xcd << 1) | (idx & 1);    // 0..15
  const int rb  = idx >> 1;                  // 0..63
  const unsigned brow = (unsigned)rb * 256u;
  const int bcol = cb * 32;

  const int wr  = (wid >> 1) * 64;           // wave rows [wr, wr+64)
  const int wcg = (wid & 1) * 16;            // wave cols [wcg, wcg+16)
  const int lrow = lane & 15;
  const int kgrp = lane >> 4;

  i32x4 acc[4][4];
  {
    i32x4 z = {0, 0, 0, 0};
#pragma unroll
    for (int g = 0; g < 4; ++g)
#pragma unroll
      for (int i = 0; i < 4; ++i) acc[g][i] = z;
  }

  const int sread = ((kgrp + (lrow >> 1)) & 3) << 4;
  const int aro = (wr + lrow) * 64 + sread;
  const int wro = (wcg + lrow) * 64 + sread;

  const int l4 = lane >> 2;
  const int kslot = (((lane & 3) - ((lane >> 3) & 3)) & 3) << 4;
  const char* sAb = (const char*)Ap + (size_t)(brow + wid * 32 + l4) * KPB + kslot;
  const char* sWb = (const char*)Wp + (size_t)(bcol + l4) * KPB + kslot;

  // prologue: half-tiles 0,1 in flight
  stage(lds, 0,    0, sAb, sWb, wid);
  stage(lds, SLOT, 1, sAb, sWb, wid);

  int rs = 0;
#define PH(CMv, NWv, STv, HT) do {                                             \
    int ws = (rs >= SLOT) ? rs - SLOT : rs + 2 * SLOT;                         \
    phase<CMv, NWv, STv>(lds, rs, ws, HT, sAb, sWb, wid, aro, wro, acc);       \
    rs = (rs == 2 * SLOT) ? 0 : rs + SLOT;                                     \
  } while (0)

  // comp masks: ht0-11 x+h (0xF) | ht12-19 c (0xB) | ht20 delt (0x8)
#pragma unroll 1
  for (int h = 0; h < 11; ++h) PH(0xF, 3, true, h + 2);
  PH(0xF, 3, true, 13);
#pragma unroll 1
  for (int h = 12; h < 19; ++h) PH(0xB, 3, true, h + 2);
  PH(0xB, 3, false, 0);    // h=19: stage(20) still in flight -> vmcnt(3)
  PH(0x8, 0, false, 0);    // h=20: drain
#undef PH

  // ---------------- fused epilogue (dequant + activations; Tv precomputed) ----------------
  const float* Tvp = out + 2 * BH;
  const int n = bcol + wcg + lrow;
  const float bi = b_ix[n], bff = b_fx[n], bc = b_cx[n], bo = b_ox[n];
  const float s0 = sw[0 * 512 + n], s1 = sw[1 * 512 + n];
  const float s3 = sw[3 * 512 + n], s4 = sw[4 * 512 + n];
  const int rbase = kgrp * 4;
#pragma unroll
  for (int i = 0; i < 4; ++i) {
    const int m0 = (int)brow + wr + 16 * i + rbase;
    const float4 sa4 = *(const float4*)(sa + m0);
#pragma unroll
    for (int r = 0; r < 4; ++r) {
      const long m   = m0 + r;
      const long off = m * H_SZ + n;
      const float sr = (r == 0) ? sa4.x : (r == 1) ? sa4.y : (r == 2) ? sa4.z : sa4.w;
      const float iv = sigm((float)acc[0][i][r] * sr * s0 + bi);
      const float fv = sigm((float)acc[1][i][r] * sr * s1 + bff);
      const float kv = tanhx((float)acc[2][i][r] * sr * s3 + bc);
      const float ov = sigm((float)acc[3][i][r] * sr * s4 + bo);
      const float Tv = Tvp[off];
      const float cp = c_prev[off];
      const float cn = iv * Tv * kv + fv * cp;
      out[off]      = ov * tanhx(cn);
      out[BH + off] = cn;
    }
  }
}

// ---------------- tgate (BM=512, single round): Tv -> out[2BH..] ----------------
// slot: A 32 KB (rows [0,512), byte = row*64 + swz) + W at 32768 {t:+0, tt:+2048}.
// Wp8 zero-padding makes both gates valid every phase (mask-free).
__device__ __forceinline__ void stage_t(char* lds, int sb, int ht,
                                        const char* sAb, const char* sWt,
                                        const char* sWu, int wid) {
  const unsigned kb = (unsigned)ht * 64u;
#pragma unroll
  for (int j = 0; j < 4; ++j)
    gld16(sAb + kb + (unsigned)j * (16u * KPB), lds + sb + (wid * 4 + j) * 1024);
  if (wid < 2)      gld16(sWt + kb, lds + sb + 32768 + wid * 1024);
  else if (wid < 4) gld16(sWu + kb, lds + sb + 32768 + 2048 + (wid - 2) * 1024);
}

__device__ __forceinline__ void comp_t(const char* lds, int sb, int wid,
                                       int lrow, int sread, i32x4 acc[2][4][2]) {
  const char* base = lds + sb;
  i32x4 a[4];
#pragma unroll
  for (int mi = 0; mi < 4; ++mi)
    a[mi] = *(const i32x4*)(base + (wid * 64 + mi * 16 + lrow) * 64 + sread);
  i32x4 b[2][2];
#pragma unroll
  for (int g = 0; g < 2; ++g)
#pragma unroll
    for (int cf = 0; cf < 2; ++cf)
      b[g][cf] = *(const i32x4*)(base + 32768 + g * 2048 + (cf * 16 + lrow) * 64 + sread);
#pragma unroll
  for (int g = 0; g < 2; ++g)
#pragma unroll
    for (int mi = 0; mi < 4; ++mi)
#pragma unroll
      for (int cf = 0; cf < 2; ++cf)
        acc[g][mi][cf] = __builtin_amdgcn_mfma_i32_16x16x64_i8(a[mi], b[g][cf],
                                                               acc[g][mi][cf], 0, 0, 0);
}

__global__ __launch_bounds__(512, 4) void tgate_kernel(
    const signed char* __restrict__ Ap, const signed char* __restrict__ Wp,
    const float* __restrict__ sa, const float* __restrict__ sw,
    const float* __restrict__ b_tx, float* __restrict__ out)
{
  __shared__ __align__(16) char lds[2 * TSLOT];   // 73728 B -> 2 wgs/CU

  const int tid  = threadIdx.x;
  const int lane = tid & 63;
  const int wid  = tid >> 6;

  const int bid = blockIdx.x;                // 512 wgs = 32 rb x 16 cb, one round
  const int xcd = bid & 7;
  const int idx = bid >> 3;                  // 0..63
  const int cb  = (xcd << 1) | (idx & 1);    // 0..15
  const int rb  = idx >> 1;                  // 0..31
  const unsigned brow = (unsigned)rb * 512u;
  const int bcol = cb * 32;

  const int lrow = lane & 15;
  const int kgrp = lane >> 4;

  i32x4 acc[2][4][2];
  {
    i32x4 z = {0, 0, 0, 0};
#pragma unroll
    for (int g = 0; g < 2; ++g)
#pragma unroll
      for (int mi = 0; mi < 4; ++mi) { acc[g][mi][0] = z; acc[g][mi][1] = z; }
  }

  const int sread = ((kgrp + (lrow >> 1)) & 3) << 4;

  const int l4 = lane >> 2;
  const int kslot = (((lane & 3) - ((lane >> 3) & 3)) & 3) << 4;
  const char* sAb = (const char*)Ap + (size_t)(brow + wid * 64 + l4) * KPB + kslot;
  const char* sWt = (const char*)Wp + 2 * (size_t)GSTR
                    + (size_t)(bcol + (wid & 1) * 16 + l4) * KPB + kslot;
  const char* sWu = (const char*)Wp + 5 * (size_t)GSTR
                    + (size_t)(bcol + (wid & 1) * 16 + l4) * KPB + kslot;

  // phases over ht = {0,1,2,3,20}; stage(h+1) -> comp(h) -> syncthreads
  stage_t(lds, 0, 0, sAb, sWt, sWu, wid);
  __syncthreads();
  stage_t(lds, TSLOT, 1, sAb, sWt, sWu, wid);
  comp_t(lds, 0, wid, lrow, sread, acc);
  __syncthreads();
  stage_t(lds, 0, 2, sAb, sWt, sWu, wid);
  comp_t(lds, TSLOT, wid, lrow, sread, acc);
  __syncthreads();
  stage_t(lds, TSLOT, 3, sAb, sWt, sWu, wid);
  comp_t(lds, 0, wid, lrow, sread, acc);
  __syncthreads();
  stage_t(lds, 0, 20, sAb, sWt, sWu, wid);
  comp_t(lds, TSLOT, wid, lrow, sread, acc);
  __syncthreads();
  comp_t(lds, 0, wid, lrow, sread, acc);

  // epilogue: Tv = sigm(t*sr*s2 + bt + sigm(tt*sr*s5))
#pragma unroll
  for (int cf = 0; cf < 2; ++cf) {
    const int n = bcol + cf * 16 + lrow;
    const float bt = b_tx[n];
    const float s2 = sw[2 * 512 + n], s5 = sw[5 * 512 + n];
#pragma unroll
    for (int mi = 0; mi < 4; ++mi) {
      const int m0 = (int)brow + wid * 64 + mi * 16 + kgrp * 4;
      const float4 sa4 = *(const float4*)(sa + m0);
#pragma unroll
      for (int r = 0; r < 4; ++r) {
        const long off = (long)(m0 + r) * H_SZ + n;
        const float sr = (r == 0) ? sa4.x : (r == 1) ? sa4.y : (r == 2) ? sa4.z : sa4.w;
        const float inner = sigm((float)acc[1][mi][cf][r] * sr * s5);
        out[2 * BH + off] = sigm((float)acc[0][mi][cf][r] * sr * s2 + bt + inner);
      }
    }
  }
}

extern "C" void kernel_launch(void* const* d_in, const int* in_sizes, int n_in,
                              void* d_out, int out_size, void* d_ws, size_t ws_size,
                              hipStream_t stream) {
  const float* x      = (const float*)d_in[0];
  const float* h      = (const float*)d_in[1];
  const float* c_prev = (const float*)d_in[2];
  const float* dl     = (const float*)d_in[3];
  const float* W_ix = (const float*)d_in[4];
  const float* b_ix = (const float*)d_in[5];
  const float* W_ih = (const float*)d_in[6];
  const float* W_ic = (const float*)d_in[7];
  const float* W_fx = (const float*)d_in[8];
  const float* b_fx = (const float*)d_in[9];
  const float* W_fh = (const float*)d_in[10];
  const float* W_fc = (const float*)d_in[11];
  const float* W_tx = (const float*)d_in[12];
  const float* b_tx = (const float*)d_in[13];
  const float* W_tt = (const float*)d_in[14];
  const float* W_cx = (const float*)d_in[15];
  const float* b_cx = (const float*)d_in[16];
  const float* W_ch = (const float*)d_in[17];
  const float* W_ox = (const float*)d_in[18];
  const float* b_ox = (const float*)d_in[19];
  const float* W_oh = (const float*)d_in[20];
  const float* W_oc = (const float*)d_in[21];
  const float* W_ot = (const float*)d_in[22];

  signed char* Ap8 = (signed char*)d_ws;                             // 22,020,096 B
  signed char* Wp8 = (signed char*)d_ws + (size_t)B_SZ * KPB;        // + 4,128,768 B
  float* sa = (float*)((char*)d_ws + (size_t)B_SZ * KPB + 6L * H_SZ * KPB);   // 64 KB
  float* sw = sa + B_SZ;                                             // 12 KB

  prep_kernel<<<4096 + 3072, 256, 0, stream>>>(
      x, h, c_prev, dl,
      W_ix, W_ih, W_ic, W_fx, W_fh, W_fc, W_tx, W_tt, W_cx, W_ch,
      W_ox, W_oh, W_oc, W_ot, Ap8, sa, Wp8, sw);

  tgate_kernel<<<512, 512, 0, stream>>>(Ap8, Wp8, sa, sw, b_tx, (float*)d_out);

  lstm_main<<<1024, 512, 0, stream>>>(Ap8, Wp8, sa, sw, c_prev,
                                      b_ix, b_fx, b_cx, b_ox,
                                      (float*)d_out);
}

// Round 21
// 116.018 us; speedup vs baseline: 1.1634x; 1.0152x over previous
//
#include <hip/hip_runtime.h>
#include <cstdint>

#define B_SZ   16384
#define H_SZ   512
#define DIN    256
#define TEMB   16
#define KP     1344            // packed K: x[0,256) h[256,768) c[768,1280) delt[1280,1296) pad
#define KPB    1344            // bytes per row (i8)
#define BH     8388608L        // B_SZ*H_SZ
#define SLOT   24576           // slot: A 16 KB (256 rows x 64 B) + 4 W regions x 2 KB
#define TVOFF  49152           // Tv stash offset (16 KB: 512 threads x 32 B)
#define GSTR   688128          // 512*KPB: gate stride in Wp8 bytes

typedef __attribute__((ext_vector_type(4))) float f32x4;
typedef __attribute__((ext_vector_type(4))) int   i32x4;

typedef const __attribute__((address_space(1))) unsigned int gu32_t;
typedef __attribute__((address_space(3)))       unsigned int lu32_t;

__device__ __forceinline__ void gld16(const void* g, void* l) {
  __builtin_amdgcn_global_load_lds((gu32_t*)(uintptr_t)g,
                                   (lu32_t*)(unsigned int)(uintptr_t)l, 16, 0, 0);
}

__device__ __forceinline__ float sigm(float v)  { return 1.0f / (1.0f + __expf(-v)); }
__device__ __forceinline__ float tanhx(float v) { return 2.0f / (1.0f + __expf(-2.0f * v)) - 1.0f; }

__device__ __forceinline__ signed char q8(float v, float inv) {
  int q = __float2int_rn(v * inv);
  q = (q > 127) ? 127 : (q < -127 ? -127 : q);
  return (signed char)q;
}

__device__ __forceinline__ unsigned short f2bf(float f) {
  unsigned int u = __float_as_uint(f);
  u += 0x7FFFu + ((u >> 16) & 1u);
  return (unsigned short)(u >> 16);
}

__device__ __forceinline__ float bf2f(unsigned short v) {
  return __uint_as_float(((unsigned int)v) << 16);
}

// ---------------- fused prep: blocks [0,4096) quantize A rows; [4096,7168) W rows ----------
__global__ void prep_kernel(const float* __restrict__ x, const float* __restrict__ h,
                            const float* __restrict__ c, const float* __restrict__ dl,
                            const float* __restrict__ Wix, const float* __restrict__ Wih, const float* __restrict__ Wic,
                            const float* __restrict__ Wfx, const float* __restrict__ Wfh, const float* __restrict__ Wfc,
                            const float* __restrict__ Wtx, const float* __restrict__ Wtt,
                            const float* __restrict__ Wcx, const float* __restrict__ Wch,
                            const float* __restrict__ Wox, const float* __restrict__ Woh,
                            const float* __restrict__ Woc, const float* __restrict__ Wot,
                            signed char* __restrict__ Ap, float* __restrict__ sa,
                            signed char* __restrict__ Wp, float* __restrict__ sw) {
  __shared__ float row[KP];
  __shared__ float red[256];
  const int tid = threadIdx.x;
  if (blockIdx.x < 4096) {
    const int lane = tid & 63;
    const int m    = blockIdx.x * 4 + (tid >> 6);
    float4 v[6];
    float lmax = 0.f;
#pragma unroll
    for (int i = 0; i < 6; ++i) {
      const int k4 = (i * 64 + lane) * 4;
      float4 t = make_float4(0.f, 0.f, 0.f, 0.f);
      if (k4 < 256)       t = *(const float4*)(x  + (size_t)m * DIN  + k4);
      else if (k4 < 768)  t = *(const float4*)(h  + (size_t)m * H_SZ + (k4 - 256));
      else if (k4 < 1280) t = *(const float4*)(c  + (size_t)m * H_SZ + (k4 - 768));
      else if (k4 < 1296) t = *(const float4*)(dl + (size_t)m * TEMB + (k4 - 1280));
      v[i] = t;
      lmax = fmaxf(lmax, fmaxf(fmaxf(fabsf(t.x), fabsf(t.y)), fmaxf(fabsf(t.z), fabsf(t.w))));
    }
#pragma unroll
    for (int s = 1; s < 64; s <<= 1)
      lmax = fmaxf(lmax, __shfl_xor(lmax, s));
    const float smax = fmaxf(lmax, 1e-20f);
    const float inv  = 127.0f / smax;
    if (lane == 0) sa[m] = smax * (1.0f / 127.0f);
#pragma unroll
    for (int i = 0; i < 6; ++i) {
      const int k4 = (i * 64 + lane) * 4;
      if (k4 < KP) {
        char4 o;
        o.x = q8(v[i].x, inv); o.y = q8(v[i].y, inv);
        o.z = q8(v[i].z, inv); o.w = q8(v[i].w, inv);
        *(char4*)(Ap + (size_t)m * KPB + k4) = o;
      }
    }
    return;
  }
  const int R = blockIdx.x - 4096;   // 0..3071
  const int g = R >> 9;
  const int n = R & 511;
  float lmax = 0.f;
  for (int i = tid; i < KP / 4; i += 256) {
    const int k4 = i * 4;
    const float* src = nullptr; long o = 0;
    if (g == 0) {
      if (k4 < 256)       { src = Wix; o = (long)n * 256 + k4; }
      else if (k4 < 768)  { src = Wih; o = (long)n * 512 + (k4 - 256); }
      else if (k4 < 1280) { src = Wic; o = (long)n * 512 + (k4 - 768); }
    } else if (g == 1) {
      if (k4 < 256)       { src = Wfx; o = (long)n * 256 + k4; }
      else if (k4 < 768)  { src = Wfh; o = (long)n * 512 + (k4 - 256); }
      else if (k4 < 1280) { src = Wfc; o = (long)n * 512 + (k4 - 768); }
    } else if (g == 2) {
      if (k4 < 256)       { src = Wtx; o = (long)n * 256 + k4; }
    } else if (g == 3) {
      if (k4 < 256)       { src = Wcx; o = (long)n * 256 + k4; }
      else if (k4 < 768)  { src = Wch; o = (long)n * 512 + (k4 - 256); }
    } else if (g == 4) {
      if (k4 < 256)       { src = Wox; o = (long)n * 256 + k4; }
      else if (k4 < 768)  { src = Woh; o = (long)n * 512 + (k4 - 256); }
      else if (k4 < 1280) { src = Woc; o = (long)n * 512 + (k4 - 768); }
      else if (k4 < 1296) { src = Wot; o = (long)n * 16 + (k4 - 1280); }
    } else {
      if (k4 >= 1280 && k4 < 1296) { src = Wtt; o = (long)n * 16 + (k4 - 1280); }
    }
    float4 v = make_float4(0.f, 0.f, 0.f, 0.f);
    if (src) v = *(const float4*)(src + o);
    *(float4*)(row + k4) = v;
    lmax = fmaxf(lmax, fmaxf(fmaxf(fabsf(v.x), fabsf(v.y)), fmaxf(fabsf(v.z), fabsf(v.w))));
  }
  red[tid] = lmax;
  __syncthreads();
  for (int s = 128; s > 0; s >>= 1) {
    if (tid < s) red[tid] = fmaxf(red[tid], red[tid + s]);
    __syncthreads();
  }
  const float smax = fmaxf(red[0], 1e-20f);
  const float inv  = 127.0f / smax;
  if (tid == 0) sw[R] = smax * (1.0f / 127.0f);
  for (int i = tid; i < KP / 4; i += 256) {
    const int k4 = i * 4;
    char4 o;
    o.x = q8(row[k4],     inv); o.y = q8(row[k4 + 1], inv);
    o.z = q8(row[k4 + 2], inv); o.w = q8(row[k4 + 3], inv);
    *(char4*)(Wp + (size_t)R * KPB + k4) = o;
  }
}

// LDS layout per slot (K-phase = 64 i8 = 64 B per row; r11..r18-verified byte math):
//   A: byte = row*64 + ((kgrp + (lrow>>1))&3)*16,  row in [0,256)
//   W: byte = 16384 + region*2048 + col*64 + swz,  col in [0,32)
// main regions {0,1,2,3} = gates {i=0,f=1,k=3,o=4}; t-loop regions {0,1} = {t=2,tt=5}.
// Inactive K-segments in Wp are ZERO -> staging is mask-free.

__device__ __forceinline__ void stage(char* lds, int sb, int ht,
                                      const char* sAb, const char* sWb, int wid) {
  const unsigned kb = (unsigned)ht * 64u;
  gld16(sAb + kb,              lds + sb + wid * 2048);
  gld16(sAb + kb + 16u * KPB,  lds + sb + wid * 2048 + 1024);
  const int r = wid >> 1, c = wid & 1;
  const int g = r + (r >> 1);                 // region -> gate: 0,1,3,4
  gld16(sWb + (unsigned)g * GSTR + (unsigned)c * (16u * KPB) + kb,
        lds + sb + 16384 + r * 2048 + c * 1024);
}

__device__ __forceinline__ void stage_tl(char* lds, int sb, int ht,
                                         const char* sAb, const char* sWb, int wid) {
  const unsigned kb = (unsigned)ht * 64u;
  gld16(sAb + kb,              lds + sb + wid * 2048);
  gld16(sAb + kb + 16u * KPB,  lds + sb + wid * 2048 + 1024);
  if (wid < 4) {
    const int r = wid >> 1, c = wid & 1;
    const int g = (r == 0) ? 2 : 5;           // region -> gate: t, tt
    gld16(sWb + (unsigned)g * GSTR + (unsigned)c * (16u * KPB) + kb,
          lds + sb + 16384 + r * 2048 + c * 1024);
  }
}

template<unsigned CM>
__device__ __forceinline__ void comp(const char* lds, int sb, int aro, int wro,
                                     i32x4 acc[4][4]) {
  const char* base = lds + sb;
  i32x4 a[4];
#pragma unroll
  for (int i = 0; i < 4; ++i)
    a[i] = *(const i32x4*)(base + aro + i * 1024);
  __builtin_amdgcn_s_setprio(1);
#pragma unroll
  for (int r = 0; r < 4; ++r) {
    if (CM & (1u << r)) {
      i32x4 b = *(const i32x4*)(base + 16384 + r * 2048 + wro);
#pragma unroll
      for (int i = 0; i < 4; ++i)
        acc[r][i] = __builtin_amdgcn_mfma_i32_16x16x64_i8(a[i], b, acc[r][i], 0, 0, 0);
    }
  }
  __builtin_amdgcn_s_setprio(0);
}

__device__ __forceinline__ void comp_tl(const char* lds, int sb, int aro, int wro,
                                        i32x4 acct[2][4]) {
  const char* base = lds + sb;
  i32x4 a[4];
#pragma unroll
  for (int i = 0; i < 4; ++i)
    a[i] = *(const i32x4*)(base + aro + i * 1024);
#pragma unroll
  for (int r = 0; r < 2; ++r) {
    i32x4 b = *(const i32x4*)(base + 16384 + r * 2048 + wro);
#pragma unroll
    for (int i = 0; i < 4; ++i)
      acct[r][i] = __builtin_amdgcn_mfma_i32_16x16x64_i8(a[i], b, acct[r][i], 0, 0, 0);
  }
}

// ---------------- fully fused kernel: t-gate pre-loop + 4-gate main loop ----------------
// peak regs = max(t-loop 32, main 64) acc + ~60 arch <= 128 -> 4 waves/SIMD;
// LDS 2*24576 + 16384 = 65536/wg -> 2 wgs/CU.
__global__ __launch_bounds__(512, 4) void lstm_main(
    const signed char* __restrict__ Ap, const signed char* __restrict__ Wp,
    const float* __restrict__ sa, const float* __restrict__ sw,
    const float* __restrict__ c_prev,
    const float* __restrict__ b_ix, const float* __restrict__ b_fx,
    const float* __restrict__ b_tx,
    const float* __restrict__ b_cx, const float* __restrict__ b_ox,
    float* __restrict__ out)
{
  __shared__ __align__(16) char lds[2 * SLOT + 16384];   // 65536 B

  const int tid  = threadIdx.x;
  const int lane = tid & 63;
  const int wid  = tid >> 6;

  const int bid = blockIdx.x;
  const int xcd = bid & 7;
  const int idx = bid >> 3;                  // 0..127
  const int cb  = (xcd << 1) | (idx & 1);    // 0..15
  const int rb  = idx >> 1;                  // 0..63
  const unsigned brow = (unsigned)rb * 256u;
  const int bcol = cb * 32;

  const int wr  = (wid >> 1) * 64;           // wave rows [wr, wr+64)
  const int wcg = (wid & 1) * 16;            // wave cols [wcg, wcg+16)
  const int lrow = lane & 15;
  const int kgrp = lane >> 4;

  const int sread = ((kgrp + (lrow >> 1)) & 3) << 4;
  const int aro = (wr + lrow) * 64 + sread;
  const int wro = (wcg + lrow) * 64 + sread;

  const int l4 = lane >> 2;
  const int kslot = (((lane & 3) - ((lane >> 3) & 3)) & 3) << 4;
  const char* sAb = (const char*)Ap + (size_t)(brow + wid * 32 + l4) * KPB + kslot;
  const char* sWb = (const char*)Wp + (size_t)(bcol + l4) * KPB + kslot;

  const int n = bcol + wcg + lrow;
  const int rbase = kgrp * 4;

  // ---------------- t-gate pre-loop: 5 phases over ht {0,1,2,3,20} ----------------
  {
    i32x4 acct[2][4];
    {
      i32x4 z = {0, 0, 0, 0};
#pragma unroll
      for (int r = 0; r < 2; ++r)
#pragma unroll
        for (int i = 0; i < 4; ++i) acct[r][i] = z;
    }
    stage_tl(lds, 0, 0, sAb, sWb, wid);
    __syncthreads();
    stage_tl(lds, SLOT, 1, sAb, sWb, wid);
    comp_tl(lds, 0, aro, wro, acct);
    __syncthreads();
    stage_tl(lds, 0, 2, sAb, sWb, wid);
    comp_tl(lds, SLOT, aro, wro, acct);
    __syncthreads();
    stage_tl(lds, SLOT, 3, sAb, sWb, wid);
    comp_tl(lds, 0, aro, wro, acct);
    __syncthreads();
    stage_tl(lds, 0, 20, sAb, sWb, wid);
    comp_tl(lds, SLOT, aro, wro, acct);
    __syncthreads();
    comp_tl(lds, 0, aro, wro, acct);

    // t-finish: Tv = sigm(t*sr*s2 + bt + sigm(tt*sr*s5)); write out[2BH]; stash bf16
    const float bt = b_tx[n];
    const float s2 = sw[2 * 512 + n], s5 = sw[5 * 512 + n];
    unsigned tvp[8];
#pragma unroll
    for (int w = 0; w < 8; ++w) tvp[w] = 0u;
#pragma unroll
    for (int i = 0; i < 4; ++i) {
      const int m0 = (int)brow + wr + 16 * i + rbase;
      const float4 sa4 = *(const float4*)(sa + m0);
#pragma unroll
      for (int r = 0; r < 4; ++r) {
        const long off = (long)(m0 + r) * H_SZ + n;
        const float sr = (r == 0) ? sa4.x : (r == 1) ? sa4.y : (r == 2) ? sa4.z : sa4.w;
        const float inner = sigm((float)acct[1][i][r] * sr * s5);
        const float tv = sigm((float)acct[0][i][r] * sr * s2 + bt + inner);
        out[2 * BH + off] = tv;
        const int ix = i * 4 + r;
        tvp[ix >> 1] |= ((unsigned)f2bf(tv)) << ((ix & 1) * 16);
      }
    }
    *(uint4*)(lds + TVOFF + tid * 32)      = make_uint4(tvp[0], tvp[1], tvp[2], tvp[3]);
    *(uint4*)(lds + TVOFF + tid * 32 + 16) = make_uint4(tvp[4], tvp[5], tvp[6], tvp[7]);
    __syncthreads();   // all t-loop slot reads drained before main staging reuses slots
  }

  // ---------------- main loop: 21 phases, ring-2 (r17-proven) ----------------
  i32x4 acc[4][4];
  {
    i32x4 z = {0, 0, 0, 0};
#pragma unroll
    for (int g = 0; g < 4; ++g)
#pragma unroll
      for (int i = 0; i < 4; ++i) acc[g][i] = z;
  }

  stage(lds, 0, 0, sAb, sWb, wid);
  __syncthreads();
  // masks: ht0-11 x+h (0xF) | ht12-19 c (0xB) | ht20 delt (0x8)
#pragma unroll 1
  for (int h = 0; h < 12; ++h) {
    stage(lds, ((h + 1) & 1) * SLOT, h + 1, sAb, sWb, wid);
    comp<0xF>(lds, (h & 1) * SLOT, aro, wro, acc);
    __syncthreads();
  }
#pragma unroll 1
  for (int h = 12; h < 20; ++h) {
    if (h < 20 - 1 + 1) {}  // (no-op; staging handled below)
    if (h + 1 <= 20) stage(lds, ((h + 1) & 1) * SLOT, h + 1, sAb, sWb, wid);
    comp<0xB>(lds, (h & 1) * SLOT, aro, wro, acc);
    __syncthreads();
  }
  comp<0x8>(lds, (20 & 1) * SLOT, aro, wro, acc);

  // ---------------- fused epilogue (dequant + activations; Tv from LDS stash) ----------
  const float bi = b_ix[n], bff = b_fx[n], bc = b_cx[n], bo = b_ox[n];
  const float s0 = sw[0 * 512 + n], s1 = sw[1 * 512 + n];
  const float s3 = sw[3 * 512 + n], s4 = sw[4 * 512 + n];
  const uint4 tw0 = *(const uint4*)(lds + TVOFF + tid * 32);
  const uint4 tw1 = *(const uint4*)(lds + TVOFF + tid * 32 + 16);
  unsigned tvp[8] = {tw0.x, tw0.y, tw0.z, tw0.w, tw1.x, tw1.y, tw1.z, tw1.w};
#pragma unroll
  for (int i = 0; i < 4; ++i) {
    const int m0 = (int)brow + wr + 16 * i + rbase;
    const float4 sa4 = *(const float4*)(sa + m0);
#pragma unroll
    for (int r = 0; r < 4; ++r) {
      const long m   = m0 + r;
      const long off = m * H_SZ + n;
      const float sr = (r == 0) ? sa4.x : (r == 1) ? sa4.y : (r == 2) ? sa4.z : sa4.w;
      const float iv = sigm((float)acc[0][i][r] * sr * s0 + bi);
      const float fv = sigm((float)acc[1][i][r] * sr * s1 + bff);
      const float kv = tanhx((float)acc[2][i][r] * sr * s3 + bc);
      const float ov = sigm((float)acc[3][i][r] * sr * s4 + bo);
      const int ix = i * 4 + r;
      const float Tv = bf2f((unsigned short)((tvp[ix >> 1] >> ((ix & 1) * 16)) & 0xFFFFu));
      const float cp = c_prev[off];
      const float cn = iv * Tv * kv + fv * cp;
      out[off]      = ov * tanhx(cn);
      out[BH + off] = cn;
    }
  }
}

extern "C" void kernel_launch(void* const* d_in, const int* in_sizes, int n_in,
                              void* d_out, int out_size, void* d_ws, size_t ws_size,
                              hipStream_t stream) {
  const float* x      = (const float*)d_in[0];
  const float* h      = (const float*)d_in[1];
  const float* c_prev = (const float*)d_in[2];
  const float* dl     = (const float*)d_in[3];
  const float* W_ix = (const float*)d_in[4];
  const float* b_ix = (const float*)d_in[5];
  const float* W_ih = (const float*)d_in[6];
  const float* W_ic = (const float*)d_in[7];
  const float* W_fx = (const float*)d_in[8];
  const float* b_fx = (const float*)d_in[9];
  const float* W_fh = (const float*)d_in[10];
  const float* W_fc = (const float*)d_in[11];
  const float* W_tx = (const float*)d_in[12];
  const float* b_tx = (const float*)d_in[13];
  const float* W_tt = (const float*)d_in[14];
  const float* W_cx = (const float*)d_in[15];
  const float* b_cx = (const float*)d_in[16];
  const float* W_ch = (const float*)d_in[17];
  const float* W_ox = (const float*)d_in[18];
  const float* b_ox = (const float*)d_in[19];
  const float* W_oh = (const float*)d_in[20];
  const float* W_oc = (const float*)d_in[21];
  const float* W_ot = (const float*)d_in[22];

  signed char* Ap8 = (signed char*)d_ws;                             // 22,020,096 B
  signed char* Wp8 = (signed char*)d_ws + (size_t)B_SZ * KPB;        // + 4,128,768 B
  float* sa = (float*)((char*)d_ws + (size_t)B_SZ * KPB + 6L * H_SZ * KPB);   // 64 KB
  float* sw = sa + B_SZ;                                             // 12 KB

  prep_kernel<<<4096 + 3072, 256, 0, stream>>>(
      x, h, c_prev, dl,
      W_ix, W_ih, W_ic, W_fx, W_fh, W_fc, W_tx, W_tt, W_cx, W_ch,
      W_ox, W_oh, W_oc, W_ot, Ap8, sa, Wp8, sw);

  lstm_main<<<1024, 512, 0, stream>>>(Ap8, Wp8, sa, sw, c_prev,
                                      b_ix, b_fx, b_tx, b_cx, b_ox,
                                      (float*)d_out);
}

// Round 22
// 110.794 us; speedup vs baseline: 1.2182x; 1.0471x over previous
//
#include <hip/hip_runtime.h>
#include <cstdint>

#define B_SZ   16384
#define H_SZ   512
#define DIN    256
#define TEMB   16
#define KP     1344            // packed K: x[0,256) h[256,768) c[768,1280) delt[1280,1296) pad
#define KPB    1344            // bytes per row (i8)
#define BH     8388608L        // B_SZ*H_SZ
#define SLOT   26624           // LDS slot: A 16 KB (256 rows x 64 B) + 5 W regions x 2 KB
#define GSTR   688128          // 512*KPB: gate stride in Wp8 bytes

typedef __attribute__((ext_vector_type(4))) float f32x4;
typedef __attribute__((ext_vector_type(4))) int   i32x4;

typedef const __attribute__((address_space(1))) unsigned int gu32_t;
typedef __attribute__((address_space(3)))       unsigned int lu32_t;

// gate -> W region (t and tt share region 4: never co-active)
__device__ constexpr int RG[6] = {0, 1, 4, 3, 2, 4};

__device__ __forceinline__ void gld16(const void* g, void* l) {
  __builtin_amdgcn_global_load_lds((gu32_t*)(uintptr_t)g,
                                   (lu32_t*)(unsigned int)(uintptr_t)l, 16, 0, 0);
}

__device__ __forceinline__ float sigm(float v)  { return 1.0f / (1.0f + __expf(-v)); }
__device__ __forceinline__ float tanhx(float v) { return 2.0f / (1.0f + __expf(-2.0f * v)) - 1.0f; }

__device__ __forceinline__ signed char q8(float v, float inv) {
  int q = __float2int_rn(v * inv);
  q = (q > 127) ? 127 : (q < -127 ? -127 : q);
  return (signed char)q;
}

// ---------------- fused prep: blocks [0,4096) quantize A rows; [4096,7168) W rows ----------
__global__ void prep_kernel(const float* __restrict__ x, const float* __restrict__ h,
                            const float* __restrict__ c, const float* __restrict__ dl,
                            const float* __restrict__ Wix, const float* __restrict__ Wih, const float* __restrict__ Wic,
                            const float* __restrict__ Wfx, const float* __restrict__ Wfh, const float* __restrict__ Wfc,
                            const float* __restrict__ Wtx, const float* __restrict__ Wtt,
                            const float* __restrict__ Wcx, const float* __restrict__ Wch,
                            const float* __restrict__ Wox, const float* __restrict__ Woh,
                            const float* __restrict__ Woc, const float* __restrict__ Wot,
                            signed char* __restrict__ Ap, float* __restrict__ sa,
                            signed char* __restrict__ Wp, float* __restrict__ sw) {
  __shared__ float row[KP];
  __shared__ float red[256];
  const int tid = threadIdx.x;
  if (blockIdx.x < 4096) {
    // ---- A rows: wave-per-row, no LDS/barriers ----
    const int lane = tid & 63;
    const int m    = blockIdx.x * 4 + (tid >> 6);
    float4 v[6];
    float lmax = 0.f;
#pragma unroll
    for (int i = 0; i < 6; ++i) {
      const int k4 = (i * 64 + lane) * 4;
      float4 t = make_float4(0.f, 0.f, 0.f, 0.f);
      if (k4 < 256)       t = *(const float4*)(x  + (size_t)m * DIN  + k4);
      else if (k4 < 768)  t = *(const float4*)(h  + (size_t)m * H_SZ + (k4 - 256));
      else if (k4 < 1280) t = *(const float4*)(c  + (size_t)m * H_SZ + (k4 - 768));
      else if (k4 < 1296) t = *(const float4*)(dl + (size_t)m * TEMB + (k4 - 1280));
      v[i] = t;
      lmax = fmaxf(lmax, fmaxf(fmaxf(fabsf(t.x), fabsf(t.y)), fmaxf(fabsf(t.z), fabsf(t.w))));
    }
#pragma unroll
    for (int s = 1; s < 64; s <<= 1)
      lmax = fmaxf(lmax, __shfl_xor(lmax, s));
    const float smax = fmaxf(lmax, 1e-20f);
    const float inv  = 127.0f / smax;
    if (lane == 0) sa[m] = smax * (1.0f / 127.0f);
#pragma unroll
    for (int i = 0; i < 6; ++i) {
      const int k4 = (i * 64 + lane) * 4;
      if (k4 < KP) {
        char4 o;
        o.x = q8(v[i].x, inv); o.y = q8(v[i].y, inv);
        o.z = q8(v[i].z, inv); o.w = q8(v[i].w, inv);
        *(char4*)(Ap + (size_t)m * KPB + k4) = o;
      }
    }
    return;
  }
  // ---- W rows ----
  const int R = blockIdx.x - 4096;   // 0..3071
  const int g = R >> 9;
  const int n = R & 511;
  float lmax = 0.f;
  for (int i = tid; i < KP / 4; i += 256) {
    const int k4 = i * 4;
    const float* src = nullptr; long o = 0;
    if (g == 0) {
      if (k4 < 256)       { src = Wix; o = (long)n * 256 + k4; }
      else if (k4 < 768)  { src = Wih; o = (long)n * 512 + (k4 - 256); }
      else if (k4 < 1280) { src = Wic; o = (long)n * 512 + (k4 - 768); }
    } else if (g == 1) {
      if (k4 < 256)       { src = Wfx; o = (long)n * 256 + k4; }
      else if (k4 < 768)  { src = Wfh; o = (long)n * 512 + (k4 - 256); }
      else if (k4 < 1280) { src = Wfc; o = (long)n * 512 + (k4 - 768); }
    } else if (g == 2) {
      if (k4 < 256)       { src = Wtx; o = (long)n * 256 + k4; }
    } else if (g == 3) {
      if (k4 < 256)       { src = Wcx; o = (long)n * 256 + k4; }
      else if (k4 < 768)  { src = Wch; o = (long)n * 512 + (k4 - 256); }
    } else if (g == 4) {
      if (k4 < 256)       { src = Wox; o = (long)n * 256 + k4; }
      else if (k4 < 768)  { src = Woh; o = (long)n * 512 + (k4 - 256); }
      else if (k4 < 1280) { src = Woc; o = (long)n * 512 + (k4 - 768); }
      else if (k4 < 1296) { src = Wot; o = (long)n * 16 + (k4 - 1280); }
    } else {
      if (k4 >= 1280 && k4 < 1296) { src = Wtt; o = (long)n * 16 + (k4 - 1280); }
    }
    float4 v = make_float4(0.f, 0.f, 0.f, 0.f);
    if (src) v = *(const float4*)(src + o);
    *(float4*)(row + k4) = v;
    lmax = fmaxf(lmax, fmaxf(fmaxf(fabsf(v.x), fabsf(v.y)), fmaxf(fabsf(v.z), fabsf(v.w))));
  }
  red[tid] = lmax;
  __syncthreads();
  for (int s = 128; s > 0; s >>= 1) {
    if (tid < s) red[tid] = fmaxf(red[tid], red[tid + s]);
    __syncthreads();
  }
  const float smax = fmaxf(red[0], 1e-20f);
  const float inv  = 127.0f / smax;
  if (tid == 0) sw[R] = smax * (1.0f / 127.0f);
  for (int i = tid; i < KP / 4; i += 256) {
    const int k4 = i * 4;
    char4 o;
    o.x = q8(row[k4],     inv); o.y = q8(row[k4 + 1], inv);
    o.z = q8(row[k4 + 2], inv); o.w = q8(row[k4 + 3], inv);
    *(char4*)(Wp + (size_t)R * KPB + k4) = o;
  }
}

// LDS layout per slot (K-phase = 64 i8 elems = 64 B per row; r11/r16-verified byte math):
//   A: byte = row*64 + ((kgrp + (lrow>>1))&3)*16,  row in [0,256)
//   W: byte = 16384 + RG[g]*2048 + col*64 + swz,   col in [0,32)
// gld16 writes 1KB chunks linearly; per-lane source granule pre-permuted (kslot).

// gates: 0=i 1=f 2=t 3=k 4=o 5=tt.  A: wave w -> chunks {2w,2w+1}.
// W (2 chunks/gate): chunk (g,c) -> wave (2g+c)&7.
template<unsigned SMASK>
__device__ __forceinline__ void stage(char* lds, int sb, int ht,
                                      const char* sAb, const char* sWb, int wid) {
  const unsigned kb = (unsigned)ht * 64u;
  gld16(sAb + kb,              lds + sb + wid * 2048);
  gld16(sAb + kb + 16u * KPB,  lds + sb + wid * 2048 + 1024);
#pragma unroll
  for (int g = 0; g < 6; ++g) {
    if (SMASK & (1u << g)) {
#pragma unroll
      for (int c = 0; c < 2; ++c) {
        if (((2 * g + c) & 7) == wid)   // wave-uniform scalar compare
          gld16(sWb + (unsigned)g * GSTR + (unsigned)c * (16u * KPB) + kb,
                lds + sb + 16384 + RG[g] * 2048 + c * 1024);
      }
    }
  }
}

template<unsigned CM>
__device__ __forceinline__ void comp(const char* lds, int sb, int aro, int wro,
                                     i32x4 acc[6][4]) {
  const char* base = lds + sb;
  i32x4 a[4];
#pragma unroll
  for (int i = 0; i < 4; ++i)
    a[i] = *(const i32x4*)(base + aro + i * 1024);
  __builtin_amdgcn_s_setprio(1);
#pragma unroll
  for (int g = 0; g < 6; ++g) {
    if (CM & (1u << g)) {
      i32x4 b = *(const i32x4*)(base + 16384 + RG[g] * 2048 + wro);
#pragma unroll
      for (int i = 0; i < 4; ++i)
        acc[g][i] = __builtin_amdgcn_mfma_i32_16x16x64_i8(a[i], b, acc[g][i], 0, 0, 0);
    }
  }
  __builtin_amdgcn_s_setprio(0);
}

// classic double-buffer phase (r16-proven): stage(h+1) -> comp(h) -> syncthreads.
template<unsigned CM, unsigned SM, bool ST>
__device__ __forceinline__ void phase(char* lds, int h, const char* sAb, const char* sWb,
                                      int wid, int aro, int wro, i32x4 acc[6][4]) {
  if (ST) stage<SM>(lds, ((h + 1) & 1) * SLOT, h + 1, sAb, sWb, wid);
  comp<CM>(lds, (h & 1) * SLOT, aro, wro, acc);
  __syncthreads();
}

// ---------------- main fused kernel (i8; 6 gates; 21 phases; r16-proven) ----------------
__global__ __launch_bounds__(512, 4) void lstm_main(
    const signed char* __restrict__ Ap, const signed char* __restrict__ Wp,
    const float* __restrict__ sa, const float* __restrict__ sw,
    const float* __restrict__ c_prev,
    const float* __restrict__ b_ix, const float* __restrict__ b_fx,
    const float* __restrict__ b_tx, const float* __restrict__ b_cx,
    const float* __restrict__ b_ox,
    float* __restrict__ out)
{
  __shared__ __align__(16) char lds[2 * SLOT];   // 53248 B

  const int tid  = threadIdx.x;
  const int lane = tid & 63;
  const int wid  = tid >> 6;

  // XCD swizzle: XCD k owns col-blocks {2k,2k+1} (W slice L2-resident)
  const int bid = blockIdx.x;
  const int xcd = bid & 7;
  const int idx = bid >> 3;                  // 0..127
  const int cb  = (xcd << 1) | (idx & 1);    // 0..15
  const int rb  = idx >> 1;                  // 0..63
  const unsigned brow = (unsigned)rb * 256u;
  const int bcol = cb * 32;

  const int wr  = (wid >> 1) * 64;           // wave rows [wr, wr+64)
  const int wcg = (wid & 1) * 16;            // wave cols [wcg, wcg+16)
  const int lrow = lane & 15;
  const int kgrp = lane >> 4;

  i32x4 acc[6][4];
  {
    i32x4 z = {0, 0, 0, 0};
#pragma unroll
    for (int g = 0; g < 6; ++g)
#pragma unroll
      for (int i = 0; i < 4; ++i) acc[g][i] = z;
  }

  // swizzled read offsets (byte math identical to r11/r16)
  const int sread = ((kgrp + (lrow >> 1)) & 3) << 4;
  const int aro = (wr + lrow) * 64 + sread;
  const int wro = (wcg + lrow) * 64 + sread;   // region-relative

  const int l4 = lane >> 2;
  const int kslot = (((lane & 3) - ((lane >> 3) & 3)) & 3) << 4;
  const char* sAb = (const char*)Ap + (size_t)(brow + wid * 32 + l4) * KPB + kslot;
  const char* sWb = (const char*)Wp + (size_t)(bcol + l4) * KPB + kslot;

  // prologue
  stage<0x1F>(lds, 0, 0, sAb, sWb, wid);
  __syncthreads();

  // 21 phases: x h0-3 (0x1F) | h h4-11 (0x1B) | c h12-19 (0x13) | delt h20 (0x30)
#pragma unroll 1
  for (int h = 0; h < 3; ++h)
    phase<0x1F, 0x1F, true>(lds, h, sAb, sWb, wid, aro, wro, acc);
  phase<0x1F, 0x1B, true>(lds, 3, sAb, sWb, wid, aro, wro, acc);
#pragma unroll 1
  for (int h = 4; h < 11; ++h)
    phase<0x1B, 0x1B, true>(lds, h, sAb, sWb, wid, aro, wro, acc);
  phase<0x1B, 0x13, true>(lds, 11, sAb, sWb, wid, aro, wro, acc);
#pragma unroll 1
  for (int h = 12; h < 19; ++h)
    phase<0x13, 0x13, true>(lds, h, sAb, sWb, wid, aro, wro, acc);
  phase<0x13, 0x30, true>(lds, 19, sAb, sWb, wid, aro, wro, acc);
  comp<0x30>(lds, (20 & 1) * SLOT, aro, wro, acc);

  // ---------------- fused epilogue (dequant + activations) ----------------
  const int n = bcol + wcg + lrow;
  const float bi  = b_ix[n], bff = b_fx[n], bt = b_tx[n], bc = b_cx[n], bo = b_ox[n];
  const float s0 = sw[0 * 512 + n], s1 = sw[1 * 512 + n], s2 = sw[2 * 512 + n];
  const float s3 = sw[3 * 512 + n], s4 = sw[4 * 512 + n], s5 = sw[5 * 512 + n];
  const int rbase = kgrp * 4;
#pragma unroll
  for (int i = 0; i < 4; ++i) {
    const int m0 = (int)brow + wr + 16 * i + rbase;
    const float4 sa4 = *(const float4*)(sa + m0);
#pragma unroll
    for (int r = 0; r < 4; ++r) {
      const long m   = m0 + r;
      const long off = m * H_SZ + n;
      const float sr = (r == 0) ? sa4.x : (r == 1) ? sa4.y : (r == 2) ? sa4.z : sa4.w;
      const float iv = sigm((float)acc[0][i][r] * sr * s0 + bi);
      const float fv = sigm((float)acc[1][i][r] * sr * s1 + bff);
      const float Tv = sigm((float)acc[2][i][r] * sr * s2 + bt
                            + sigm((float)acc[5][i][r] * sr * s5));
      const float kv = tanhx((float)acc[3][i][r] * sr * s3 + bc);
      const float ov = sigm((float)acc[4][i][r] * sr * s4 + bo);
      const float cp = c_prev[off];
      const float cn = iv * Tv * kv + fv * cp;
      out[off]          = ov * tanhx(cn);
      out[BH + off]     = cn;
      out[2 * BH + off] = Tv;
    }
  }
}

extern "C" void kernel_launch(void* const* d_in, const int* in_sizes, int n_in,
                              void* d_out, int out_size, void* d_ws, size_t ws_size,
                              hipStream_t stream) {
  const float* x      = (const float*)d_in[0];
  const float* h      = (const float*)d_in[1];
  const float* c_prev = (const float*)d_in[2];
  const float* dl     = (const float*)d_in[3];
  const float* W_ix = (const float*)d_in[4];
  const float* b_ix = (const float*)d_in[5];
  const float* W_ih = (const float*)d_in[6];
  const float* W_ic = (const float*)d_in[7];
  const float* W_fx = (const float*)d_in[8];
  const float* b_fx = (const float*)d_in[9];
  const float* W_fh = (const float*)d_in[10];
  const float* W_fc = (const float*)d_in[11];
  const float* W_tx = (const float*)d_in[12];
  const float* b_tx = (const float*)d_in[13];
  const float* W_tt = (const float*)d_in[14];
  const float* W_cx = (const float*)d_in[15];
  const float* b_cx = (const float*)d_in[16];
  const float* W_ch = (const float*)d_in[17];
  const float* W_ox = (const float*)d_in[18];
  const float* b_ox = (const float*)d_in[19];
  const float* W_oh = (const float*)d_in[20];
  const float* W_oc = (const float*)d_in[21];
  const float* W_ot = (const float*)d_in[22];

  signed char* Ap8 = (signed char*)d_ws;                             // 22,020,096 B
  signed char* Wp8 = (signed char*)d_ws + (size_t)B_SZ * KPB;        // + 4,128,768 B
  float* sa = (float*)((char*)d_ws + (size_t)B_SZ * KPB + 6L * H_SZ * KPB);   // 64 KB
  float* sw = sa + B_SZ;                                             // 12 KB

  prep_kernel<<<4096 + 3072, 256, 0, stream>>>(
      x, h, c_prev, dl,
      W_ix, W_ih, W_ic, W_fx, W_fh, W_fc, W_tx, W_tt, W_cx, W_ch,
      W_ox, W_oh, W_oc, W_ot, Ap8, sa, Wp8, sw);

  lstm_main<<<1024, 512, 0, stream>>>(Ap8, Wp8, sa, sw, c_prev,
                                      b_ix, b_fx, b_tx, b_cx, b_ox,
                                      (float*)d_out);
}

// Round 23
// 110.171 us; speedup vs baseline: 1.2251x; 1.0057x over previous
//
#include <hip/hip_runtime.h>
#include <cstdint>

#define B_SZ   16384
#define H_SZ   512
#define DIN    256
#define TEMB   16
#define KP     1344            // packed K: x[0,256) h[256,768) c[768,1280) delt[1280,1296) pad
#define KPB    1344            // bytes per row (i8)
#define BH     8388608L        // B_SZ*H_SZ
#define SLOT   26624           // LDS slot: A 16 KB (256 rows x 64 B) + 5 W regions x 2 KB
#define GSTR   688128          // 512*KPB: gate stride in Wp8 bytes

typedef __attribute__((ext_vector_type(4))) float f32x4;
typedef __attribute__((ext_vector_type(4))) int   i32x4;

typedef const __attribute__((address_space(1))) unsigned int gu32_t;
typedef __attribute__((address_space(3)))       unsigned int lu32_t;

// gate -> W region (t and tt share region 4: never co-active)
__device__ constexpr int RG[6] = {0, 1, 4, 3, 2, 4};

__device__ __forceinline__ void gld16(const void* g, void* l) {
  __builtin_amdgcn_global_load_lds((gu32_t*)(uintptr_t)g,
                                   (lu32_t*)(unsigned int)(uintptr_t)l, 16, 0, 0);
}

__device__ __forceinline__ float sigm(float v)  { return 1.0f / (1.0f + __expf(-v)); }
__device__ __forceinline__ float tanhx(float v) { return 2.0f / (1.0f + __expf(-2.0f * v)) - 1.0f; }

__device__ __forceinline__ signed char q8(float v, float inv) {
  int q = __float2int_rn(v * inv);
  q = (q > 127) ? 127 : (q < -127 ? -127 : q);
  return (signed char)q;
}

// ---------------- fused prep (all wave-per-row, no LDS/barriers) ----------------
// blocks [0,4096): A rows (4 rows/block).  blocks [4096,4864): W rows (4 rows/block).
__global__ void prep_kernel(const float* __restrict__ x, const float* __restrict__ h,
                            const float* __restrict__ c, const float* __restrict__ dl,
                            const float* __restrict__ Wix, const float* __restrict__ Wih, const float* __restrict__ Wic,
                            const float* __restrict__ Wfx, const float* __restrict__ Wfh, const float* __restrict__ Wfc,
                            const float* __restrict__ Wtx, const float* __restrict__ Wtt,
                            const float* __restrict__ Wcx, const float* __restrict__ Wch,
                            const float* __restrict__ Wox, const float* __restrict__ Woh,
                            const float* __restrict__ Woc, const float* __restrict__ Wot,
                            signed char* __restrict__ Ap, float* __restrict__ sa,
                            signed char* __restrict__ Wp, float* __restrict__ sw) {
  const int tid  = threadIdx.x;
  const int lane = tid & 63;
  float4 v[6];
  float lmax = 0.f;

  if (blockIdx.x < 4096) {
    // ---- A row m = [x|h|c|delt|0] ----
    const int m = blockIdx.x * 4 + (tid >> 6);
#pragma unroll
    for (int i = 0; i < 6; ++i) {
      const int k4 = (i * 64 + lane) * 4;
      float4 t = make_float4(0.f, 0.f, 0.f, 0.f);
      if (k4 < 256)       t = *(const float4*)(x  + (size_t)m * DIN  + k4);
      else if (k4 < 768)  t = *(const float4*)(h  + (size_t)m * H_SZ + (k4 - 256));
      else if (k4 < 1280) t = *(const float4*)(c  + (size_t)m * H_SZ + (k4 - 768));
      else if (k4 < 1296) t = *(const float4*)(dl + (size_t)m * TEMB + (k4 - 1280));
      v[i] = t;
      lmax = fmaxf(lmax, fmaxf(fmaxf(fabsf(t.x), fabsf(t.y)), fmaxf(fabsf(t.z), fabsf(t.w))));
    }
#pragma unroll
    for (int s = 1; s < 64; s <<= 1)
      lmax = fmaxf(lmax, __shfl_xor(lmax, s));
    const float smax = fmaxf(lmax, 1e-20f);
    const float inv  = 127.0f / smax;
    if (lane == 0) sa[m] = smax * (1.0f / 127.0f);
#pragma unroll
    for (int i = 0; i < 6; ++i) {
      const int k4 = (i * 64 + lane) * 4;
      if (k4 < KP) {
        char4 o;
        o.x = q8(v[i].x, inv); o.y = q8(v[i].y, inv);
        o.z = q8(v[i].z, inv); o.w = q8(v[i].w, inv);
        *(char4*)(Ap + (size_t)m * KPB + k4) = o;
      }
    }
    return;
  }

  // ---- W row R in packed-gate layout ----
  const int R = (blockIdx.x - 4096) * 4 + (tid >> 6);   // 0..3071
  const int g = R >> 9;
  const int n = R & 511;
#pragma unroll
  for (int i = 0; i < 6; ++i) {
    const int k4 = (i * 64 + lane) * 4;
    const float* src = nullptr; long o = 0;
    if (g == 0) {
      if (k4 < 256)       { src = Wix; o = (long)n * 256 + k4; }
      else if (k4 < 768)  { src = Wih; o = (long)n * 512 + (k4 - 256); }
      else if (k4 < 1280) { src = Wic; o = (long)n * 512 + (k4 - 768); }
    } else if (g == 1) {
      if (k4 < 256)       { src = Wfx; o = (long)n * 256 + k4; }
      else if (k4 < 768)  { src = Wfh; o = (long)n * 512 + (k4 - 256); }
      else if (k4 < 1280) { src = Wfc; o = (long)n * 512 + (k4 - 768); }
    } else if (g == 2) {
      if (k4 < 256)       { src = Wtx; o = (long)n * 256 + k4; }
    } else if (g == 3) {
      if (k4 < 256)       { src = Wcx; o = (long)n * 256 + k4; }
      else if (k4 < 768)  { src = Wch; o = (long)n * 512 + (k4 - 256); }
    } else if (g == 4) {
      if (k4 < 256)       { src = Wox; o = (long)n * 256 + k4; }
      else if (k4 < 768)  { src = Woh; o = (long)n * 512 + (k4 - 256); }
      else if (k4 < 1280) { src = Woc; o = (long)n * 512 + (k4 - 768); }
      else if (k4 < 1296) { src = Wot; o = (long)n * 16 + (k4 - 1280); }
    } else {
      if (k4 >= 1280 && k4 < 1296) { src = Wtt; o = (long)n * 16 + (k4 - 1280); }
    }
    float4 t = make_float4(0.f, 0.f, 0.f, 0.f);
    if (src) t = *(const float4*)(src + o);
    v[i] = t;
    lmax = fmaxf(lmax, fmaxf(fmaxf(fabsf(t.x), fabsf(t.y)), fmaxf(fabsf(t.z), fabsf(t.w))));
  }
#pragma unroll
  for (int s = 1; s < 64; s <<= 1)
    lmax = fmaxf(lmax, __shfl_xor(lmax, s));
  const float smax = fmaxf(lmax, 1e-20f);
  const float inv  = 127.0f / smax;
  if (lane == 0) sw[R] = smax * (1.0f / 127.0f);
#pragma unroll
  for (int i = 0; i < 6; ++i) {
    const int k4 = (i * 64 + lane) * 4;
    if (k4 < KP) {
      char4 o;
      o.x = q8(v[i].x, inv); o.y = q8(v[i].y, inv);
      o.z = q8(v[i].z, inv); o.w = q8(v[i].w, inv);
      *(char4*)(Wp + (size_t)R * KPB + k4) = o;
    }
  }
}

// LDS layout per slot (K-phase = 64 i8 elems = 64 B per row; r11/r16-verified byte math):
//   A: byte = row*64 + ((kgrp + (lrow>>1))&3)*16,  row in [0,256)
//   W: byte = 16384 + RG[g]*2048 + col*64 + swz,   col in [0,32)
// gld16 writes 1KB chunks linearly; per-lane source granule pre-permuted (kslot).

// gates: 0=i 1=f 2=t 3=k 4=o 5=tt.  A: wave w -> chunks {2w,2w+1}.
// W (2 chunks/gate): chunk (g,c) -> wave (2g+c)&7.
template<unsigned SMASK>
__device__ __forceinline__ void stage(char* lds, int sb, int ht,
                                      const char* sAb, const char* sWb, int wid) {
  const unsigned kb = (unsigned)ht * 64u;
  gld16(sAb + kb,              lds + sb + wid * 2048);
  gld16(sAb + kb + 16u * KPB,  lds + sb + wid * 2048 + 1024);
#pragma unroll
  for (int g = 0; g < 6; ++g) {
    if (SMASK & (1u << g)) {
#pragma unroll
      for (int c = 0; c < 2; ++c) {
        if (((2 * g + c) & 7) == wid)   // wave-uniform scalar compare
          gld16(sWb + (unsigned)g * GSTR + (unsigned)c * (16u * KPB) + kb,
                lds + sb + 16384 + RG[g] * 2048 + c * 1024);
      }
    }
  }
}

template<unsigned CM>
__device__ __forceinline__ void comp(const char* lds, int sb, int aro, int wro,
                                     i32x4 acc[6][4]) {
  const char* base = lds + sb;
  i32x4 a[4];
#pragma unroll
  for (int i = 0; i < 4; ++i)
    a[i] = *(const i32x4*)(base + aro + i * 1024);
  __builtin_amdgcn_s_setprio(1);
#pragma unroll
  for (int g = 0; g < 6; ++g) {
    if (CM & (1u << g)) {
      i32x4 b = *(const i32x4*)(base + 16384 + RG[g] * 2048 + wro);
#pragma unroll
      for (int i = 0; i < 4; ++i)
        acc[g][i] = __builtin_amdgcn_mfma_i32_16x16x64_i8(a[i], b, acc[g][i], 0, 0, 0);
    }
  }
  __builtin_amdgcn_s_setprio(0);
}

// classic double-buffer phase (r16/r22-proven): stage(h+1) -> comp(h) -> syncthreads.
template<unsigned CM, unsigned SM, bool ST>
__device__ __forceinline__ void phase(char* lds, int h, const char* sAb, const char* sWb,
                                      int wid, int aro, int wro, i32x4 acc[6][4]) {
  if (ST) stage<SM>(lds, ((h + 1) & 1) * SLOT, h + 1, sAb, sWb, wid);
  comp<CM>(lds, (h & 1) * SLOT, aro, wro, acc);
  __syncthreads();
}

// ---------------- main fused kernel (i8; 6 gates; 21 phases; r16/r22-proven) ----------------
__global__ __launch_bounds__(512, 4) void lstm_main(
    const signed char* __restrict__ Ap, const signed char* __restrict__ Wp,
    const float* __restrict__ sa, const float* __restrict__ sw,
    const float* __restrict__ c_prev,
    const float* __restrict__ b_ix, const float* __restrict__ b_fx,
    const float* __restrict__ b_tx, const float* __restrict__ b_cx,
    const float* __restrict__ b_ox,
    float* __restrict__ out)
{
  __shared__ __align__(16) char lds[2 * SLOT];   // 53248 B

  const int tid  = threadIdx.x;
  const int lane = tid & 63;
  const int wid  = tid >> 6;

  // XCD swizzle: XCD k owns col-blocks {2k,2k+1} (W slice L2-resident)
  const int bid = blockIdx.x;
  const int xcd = bid & 7;
  const int idx = bid >> 3;                  // 0..127
  const int cb  = (xcd << 1) | (idx & 1);    // 0..15
  const int rb  = idx >> 1;                  // 0..63
  const unsigned brow = (unsigned)rb * 256u;
  const int bcol = cb * 32;

  const int wr  = (wid >> 1) * 64;           // wave rows [wr, wr+64)
  const int wcg = (wid & 1) * 16;            // wave cols [wcg, wcg+16)
  const int lrow = lane & 15;
  const int kgrp = lane >> 4;

  i32x4 acc[6][4];
  {
    i32x4 z = {0, 0, 0, 0};
#pragma unroll
    for (int g = 0; g < 6; ++g)
#pragma unroll
      for (int i = 0; i < 4; ++i) acc[g][i] = z;
  }

  // swizzled read offsets (byte math identical to r11/r16)
  const int sread = ((kgrp + (lrow >> 1)) & 3) << 4;
  const int aro = (wr + lrow) * 64 + sread;
  const int wro = (wcg + lrow) * 64 + sread;   // region-relative

  const int l4 = lane >> 2;
  const int kslot = (((lane & 3) - ((lane >> 3) & 3)) & 3) << 4;
  const char* sAb = (const char*)Ap + (size_t)(brow + wid * 32 + l4) * KPB + kslot;
  const char* sWb = (const char*)Wp + (size_t)(bcol + l4) * KPB + kslot;

  // prologue
  stage<0x1F>(lds, 0, 0, sAb, sWb, wid);
  __syncthreads();

  // 21 phases: x h0-3 (0x1F) | h h4-11 (0x1B) | c h12-19 (0x13) | delt h20 (0x30)
#pragma unroll 1
  for (int h = 0; h < 3; ++h)
    phase<0x1F, 0x1F, true>(lds, h, sAb, sWb, wid, aro, wro, acc);
  phase<0x1F, 0x1B, true>(lds, 3, sAb, sWb, wid, aro, wro, acc);
#pragma unroll 1
  for (int h = 4; h < 11; ++h)
    phase<0x1B, 0x1B, true>(lds, h, sAb, sWb, wid, aro, wro, acc);
  phase<0x1B, 0x13, true>(lds, 11, sAb, sWb, wid, aro, wro, acc);
#pragma unroll 1
  for (int h = 12; h < 19; ++h)
    phase<0x13, 0x13, true>(lds, h, sAb, sWb, wid, aro, wro, acc);
  phase<0x13, 0x30, true>(lds, 19, sAb, sWb, wid, aro, wro, acc);
  comp<0x30>(lds, (20 & 1) * SLOT, aro, wro, acc);

  // ---------------- fused epilogue (dequant + activations) ----------------
  const int n = bcol + wcg + lrow;
  const float bi  = b_ix[n], bff = b_fx[n], bt = b_tx[n], bc = b_cx[n], bo = b_ox[n];
  const float s0 = sw[0 * 512 + n], s1 = sw[1 * 512 + n], s2 = sw[2 * 512 + n];
  const float s3 = sw[3 * 512 + n], s4 = sw[4 * 512 + n], s5 = sw[5 * 512 + n];
  const int rbase = kgrp * 4;
#pragma unroll
  for (int i = 0; i < 4; ++i) {
    const int m0 = (int)brow + wr + 16 * i + rbase;
    const float4 sa4 = *(const float4*)(sa + m0);
#pragma unroll
    for (int r = 0; r < 4; ++r) {
      const long m   = m0 + r;
      const long off = m * H_SZ + n;
      const float sr = (r == 0) ? sa4.x : (r == 1) ? sa4.y : (r == 2) ? sa4.z : sa4.w;
      const float iv = sigm((float)acc[0][i][r] * sr * s0 + bi);
      const float fv = sigm((float)acc[1][i][r] * sr * s1 + bff);
      const float Tv = sigm((float)acc[2][i][r] * sr * s2 + bt
                            + sigm((float)acc[5][i][r] * sr * s5));
      const float kv = tanhx((float)acc[3][i][r] * sr * s3 + bc);
      const float ov = sigm((float)acc[4][i][r] * sr * s4 + bo);
      const float cp = c_prev[off];
      const float cn = iv * Tv * kv + fv * cp;
      out[off]          = ov * tanhx(cn);
      out[BH + off]     = cn;
      out[2 * BH + off] = Tv;
    }
  }
}

extern "C" void kernel_launch(void* const* d_in, const int* in_sizes, int n_in,
                              void* d_out, int out_size, void* d_ws, size_t ws_size,
                              hipStream_t stream) {
  const float* x      = (const float*)d_in[0];
  const float* h      = (const float*)d_in[1];
  const float* c_prev = (const float*)d_in[2];
  const float* dl     = (const float*)d_in[3];
  const float* W_ix = (const float*)d_in[4];
  const float* b_ix = (const float*)d_in[5];
  const float* W_ih = (const float*)d_in[6];
  const float* W_ic = (const float*)d_in[7];
  const float* W_fx = (const float*)d_in[8];
  const float* b_fx = (const float*)d_in[9];
  const float* W_fh = (const float*)d_in[10];
  const float* W_fc = (const float*)d_in[11];
  const float* W_tx = (const float*)d_in[12];
  const float* b_tx = (const float*)d_in[13];
  const float* W_tt = (const float*)d_in[14];
  const float* W_cx = (const float*)d_in[15];
  const float* b_cx = (const float*)d_in[16];
  const float* W_ch = (const float*)d_in[17];
  const float* W_ox = (const float*)d_in[18];
  const float* b_ox = (const float*)d_in[19];
  const float* W_oh = (const float*)d_in[20];
  const float* W_oc = (const float*)d_in[21];
  const float* W_ot = (const float*)d_in[22];

  signed char* Ap8 = (signed char*)d_ws;                             // 22,020,096 B
  signed char* Wp8 = (signed char*)d_ws + (size_t)B_SZ * KPB;        // + 4,128,768 B
  float* sa = (float*)((char*)d_ws + (size_t)B_SZ * KPB + 6L * H_SZ * KPB);   // 64 KB
  float* sw = sa + B_SZ;                                             // 12 KB

  prep_kernel<<<4096 + 768, 256, 0, stream>>>(
      x, h, c_prev, dl,
      W_ix, W_ih, W_ic, W_fx, W_fh, W_fc, W_tx, W_tt, W_cx, W_ch,
      W_ox, W_oh, W_oc, W_ot, Ap8, sa, Wp8, sw);

  lstm_main<<<1024, 512, 0, stream>>>(Ap8, Wp8, sa, sw, c_prev,
                                      b_ix, b_fx, b_tx, b_cx, b_ox,
                                      (float*)d_out);
}